// Round 1
// baseline (245.664 us; speedup 1.0000x reference)
//
#include <hip/hip_runtime.h>

// Problem constants (reference: B=8, T=2048, C=1024, H=64)
#define B_ 8
#define T_ 2048
#define C_ 1024
#define H_ 64

typedef __bf16 bf16x8 __attribute__((ext_vector_type(8)));
typedef float  f32x4  __attribute__((ext_vector_type(4)));
typedef unsigned short u16x8 __attribute__((ext_vector_type(8)));

// round-half-up f32 -> bf16 bits (bias < 0.5 ulp; inputs are normal floats)
__device__ __forceinline__ unsigned short f2bf(float f) {
    unsigned u = __builtin_bit_cast(unsigned, f);
    u += 0x8000u;
    return (unsigned short)(u >> 16);
}

__device__ __forceinline__ unsigned pack2(float lo, float hi) {
    unsigned a = __builtin_bit_cast(unsigned, lo) + 0x8000u;
    unsigned b = __builtin_bit_cast(unsigned, hi) + 0x8000u;
    return (a >> 16) | (b & 0xffff0000u);
}

union U8 { unsigned u32[4]; u16x8 v; };

// load 8 contiguous fp32, convert to bf16x8 fragment
__device__ __forceinline__ bf16x8 load8_cvt(const float* p) {
    float4 f0 = *(const float4*)p;
    float4 f1 = *(const float4*)(p + 4);
    U8 r;
    r.u32[0] = pack2(f0.x, f0.y);
    r.u32[1] = pack2(f0.z, f0.w);
    r.u32[2] = pack2(f1.x, f1.y);
    r.u32[3] = pack2(f1.z, f1.w);
    return __builtin_bit_cast(bf16x8, r.v);
}

__device__ __forceinline__ bf16x8 load8_bf(const unsigned short* p) {
    return __builtin_bit_cast(bf16x8, *(const u16x8*)p);
}

// ---------------------------------------------------------------------------
// Kernel 0: pack Wq,Wk,Wv (fp32 [C][H]) into combined transposed bf16 Wt[192][C]
// rows 0..63 = Wq^T, 64..127 = Wk^T, 128..191 = Wv^T.  (B-operand of MFMA wants
// lane n=lane&15 reading row n of W^T with k contiguous.)
// ---------------------------------------------------------------------------
__global__ void cast_weights(const float* __restrict__ Wq,
                             const float* __restrict__ Wk,
                             const float* __restrict__ Wv,
                             unsigned short* __restrict__ Wt) {
    int idx = blockIdx.x * blockDim.x + threadIdx.x;   // 0 .. 3*C*H
    int w   = idx / (C_ * H_);
    int rem = idx % (C_ * H_);
    int c   = rem % C_;        // fastest -> coalesced Wt writes
    int h   = rem / C_;
    const float* W = (w == 0) ? Wq : (w == 1) ? Wk : Wv;
    Wt[(size_t)(w * H_ + h) * C_ + c] = f2bf(W[(size_t)c * H_ + h]);
}

// ---------------------------------------------------------------------------
// Kernel 1: fused QKV projection.  256 blocks x 256 threads; block = 64 rows of
// x (flat [B*T][C]); wave w owns rows 16w..16w+15.  A-fragments loaded straight
// from global x (fp32 -> bf16 in register, each element touched once); B-frags
// from Wt (L1/L2 resident, 24KB per k-step).  No LDS, no barriers.
// Outputs: Qb,Kb bf16 [B*T][H];  VTb bf16 [B][H][T] (transposed for PV).
// ---------------------------------------------------------------------------
__global__ __launch_bounds__(256) void qkv_proj(
        const float* __restrict__ x,
        const unsigned short* __restrict__ Wt,
        unsigned short* __restrict__ Qb,
        unsigned short* __restrict__ Kb,
        unsigned short* __restrict__ VTb) {
    const int tid  = threadIdx.x;
    const int wave = tid >> 6;
    const int lane = tid & 63;
    const int l16  = lane & 15;
    const int quad = lane >> 4;
    const size_t r0 = (size_t)blockIdx.x * 64;

    const float* xrow = x + (r0 + wave * 16 + l16) * C_ + quad * 8;

    f32x4 acc[12];
#pragma unroll
    for (int i = 0; i < 12; i++) acc[i] = (f32x4){0.f, 0.f, 0.f, 0.f};

    for (int k0 = 0; k0 < C_; k0 += 64) {
        bf16x8 a0 = load8_cvt(xrow + k0);
        bf16x8 a1 = load8_cvt(xrow + k0 + 32);
#pragma unroll
        for (int nt = 0; nt < 12; nt++) {
            const unsigned short* brow =
                Wt + (size_t)(nt * 16 + l16) * C_ + k0 + quad * 8;
            bf16x8 b0 = load8_bf(brow);
            bf16x8 b1 = load8_bf(brow + 32);
            acc[nt] = __builtin_amdgcn_mfma_f32_16x16x32_bf16(a0, b0, acc[nt], 0, 0, 0);
            acc[nt] = __builtin_amdgcn_mfma_f32_16x16x32_bf16(a1, b1, acc[nt], 0, 0, 0);
        }
    }

    // epilogue: C/D layout col=l16, row=quad*4+reg
    const int mrow_base = (int)r0 + wave * 16 + quad * 4;
#pragma unroll
    for (int nt = 0; nt < 12; nt++) {
#pragma unroll
        for (int r = 0; r < 4; r++) {
            int row = mrow_base + r;                  // global flat row in [0, B*T)
            unsigned short bv = f2bf(acc[nt][r]);
            if (nt < 4) {
                Qb[(size_t)row * H_ + nt * 16 + l16] = bv;
            } else if (nt < 8) {
                Kb[(size_t)row * H_ + (nt - 4) * 16 + l16] = bv;
            } else {
                int h = (nt - 8) * 16 + l16;
                int b = row >> 11;                    // /T_
                int t = row & (T_ - 1);
                VTb[((size_t)b * H_ + h) * T_ + t] = bv;
            }
        }
    }
}

// ---------------------------------------------------------------------------
// Kernel 2: flash attention with causal mask.  Block = (batch b, 64-row Q tile).
// 4 waves, wave w owns query rows q0+16w..+15 (Q frags held in registers the
// whole kernel).  Per KV tile (64 keys): stage K tile + V^T tile to LDS
// (stride 72 bf16 -> max 2-way bank aliasing on b128 frag reads), QK^T via
// MFMA, online softmax with quad(16-lane)-level reductions, P -> wave-private
// LDS region to convert C-layout -> A-layout, PV via MFMA.
// ---------------------------------------------------------------------------
#define ASTRIDE 72

__global__ __launch_bounds__(256) void attn(
        const unsigned short* __restrict__ Qb,
        const unsigned short* __restrict__ Kb,
        const unsigned short* __restrict__ VTb,
        float* __restrict__ out) {
    __shared__ __attribute__((aligned(16))) unsigned short ks_[64 * ASTRIDE];
    __shared__ __attribute__((aligned(16))) unsigned short vs_[H_ * ASTRIDE];
    __shared__ __attribute__((aligned(16))) unsigned short ps_[4 * 16 * ASTRIDE];

    const int tid  = threadIdx.x;
    const int wave = tid >> 6;
    const int lane = tid & 63;
    const int l16  = lane & 15;
    const int quad = lane >> 4;
    const int b    = blockIdx.x >> 5;   // / 32 q-tiles
    const int qt   = blockIdx.x & 31;
    const int q0   = qt * 64;

    // Q fragments: A[m=l16][k=quad*8+j], rows q0+16w+l16, held in registers
    const unsigned short* qrow =
        Qb + ((size_t)b * T_ + q0 + wave * 16 + l16) * H_ + quad * 8;
    bf16x8 qf0 = load8_bf(qrow);
    bf16x8 qf1 = load8_bf(qrow + 32);

    f32x4 o[4];
#pragma unroll
    for (int i = 0; i < 4; i++) o[i] = (f32x4){0.f, 0.f, 0.f, 0.f};
    float m_run[4], l_run[4];
#pragma unroll
    for (int r = 0; r < 4; r++) { m_run[r] = -1e30f; l_run[r] = 0.f; }

    const float scale = 0.125f;  // 1/sqrt(H)

    for (int j = 0; j <= qt; j++) {
        __syncthreads();
        // stage K tile [64 keys][64 h] and V^T tile [64 h][64 keys] (bf16)
#pragma unroll
        for (int i = 0; i < 2; i++) {
            int f   = tid + i * 256;      // 0..511, 8 elems each
            int row = f >> 3;
            int cg  = f & 7;
            u16x8 kv = *(const u16x8*)(Kb + ((size_t)b * T_ + j * 64 + row) * H_ + cg * 8);
            *(u16x8*)(&ks_[row * ASTRIDE + cg * 8]) = kv;
            u16x8 vv = *(const u16x8*)(VTb + ((size_t)b * H_ + row) * T_ + j * 64 + cg * 8);
            *(u16x8*)(&vs_[row * ASTRIDE + cg * 8]) = vv;
        }
        __syncthreads();

        // S = Q K^T  (4 n-tiles of 16)
        f32x4 s[4];
#pragma unroll
        for (int nt = 0; nt < 4; nt++) {
            const unsigned short* krow = &ks_[(nt * 16 + l16) * ASTRIDE + quad * 8];
            bf16x8 kf0 = load8_bf(krow);
            bf16x8 kf1 = load8_bf(krow + 32);
            f32x4 z = (f32x4){0.f, 0.f, 0.f, 0.f};
            z = __builtin_amdgcn_mfma_f32_16x16x32_bf16(qf0, kf0, z, 0, 0, 0);
            z = __builtin_amdgcn_mfma_f32_16x16x32_bf16(qf1, kf1, z, 0, 0, 0);
            s[nt] = z;
        }

        // scale; causal mask only on the diagonal tile (j<qt tiles are fully unmasked)
#pragma unroll
        for (int nt = 0; nt < 4; nt++)
#pragma unroll
            for (int r = 0; r < 4; r++) s[nt][r] *= scale;
        if (j == qt) {
#pragma unroll
            for (int nt = 0; nt < 4; nt++) {
                int n = nt * 16 + l16;                 // local key col
#pragma unroll
                for (int r = 0; r < 4; r++) {
                    int trow = wave * 16 + quad * 4 + r;  // local query row
                    if (n > trow) s[nt][r] = -1e30f;
                }
            }
        }

        // row max over 64 cols: per-lane max over n-tiles, then 16-lane quad reduce
        float alpha[4];
#pragma unroll
        for (int r = 0; r < 4; r++) {
            float v = fmaxf(fmaxf(s[0][r], s[1][r]), fmaxf(s[2][r], s[3][r]));
            v = fmaxf(v, __shfl_xor(v, 1));
            v = fmaxf(v, __shfl_xor(v, 2));
            v = fmaxf(v, __shfl_xor(v, 4));
            v = fmaxf(v, __shfl_xor(v, 8));
            float m_new = fmaxf(m_run[r], v);
            alpha[r] = __expf(m_run[r] - m_new);
            m_run[r] = m_new;
        }

        // P = exp(s - m_new): write bf16 to wave-private LDS, accumulate row sums
        float rsum[4] = {0.f, 0.f, 0.f, 0.f};
#pragma unroll
        for (int nt = 0; nt < 4; nt++) {
#pragma unroll
            for (int r = 0; r < 4; r++) {
                float p = __expf(s[nt][r] - m_run[r]);
                rsum[r] += p;
                ps_[(wave * 16 + quad * 4 + r) * ASTRIDE + nt * 16 + l16] = f2bf(p);
            }
        }
#pragma unroll
        for (int r = 0; r < 4; r++) {
            float v = rsum[r];
            v += __shfl_xor(v, 1);
            v += __shfl_xor(v, 2);
            v += __shfl_xor(v, 4);
            v += __shfl_xor(v, 8);
            l_run[r] = l_run[r] * alpha[r] + v;
        }

        // rescale O accumulators (same row=quad*4+reg mapping as S)
#pragma unroll
        for (int ht = 0; ht < 4; ht++)
#pragma unroll
            for (int r = 0; r < 4; r++) o[ht][r] *= alpha[r];

        // PV: A = P (LDS round-trip gives A-layout), B = V^T rows (contiguous)
#pragma unroll
        for (int ks = 0; ks < 2; ks++) {
            const unsigned short* prow =
                &ps_[(wave * 16 + l16) * ASTRIDE + ks * 32 + quad * 8];
            bf16x8 pf = load8_bf(prow);
#pragma unroll
            for (int ht = 0; ht < 4; ht++) {
                const unsigned short* vrow =
                    &vs_[(ht * 16 + l16) * ASTRIDE + ks * 32 + quad * 8];
                bf16x8 vf = load8_bf(vrow);
                o[ht] = __builtin_amdgcn_mfma_f32_16x16x32_bf16(pf, vf, o[ht], 0, 0, 0);
            }
        }
    }

    // epilogue: out fp32 [B][T][H]
#pragma unroll
    for (int ht = 0; ht < 4; ht++) {
#pragma unroll
        for (int r = 0; r < 4; r++) {
            int t = q0 + wave * 16 + quad * 4 + r;
            out[((size_t)b * T_ + t) * H_ + ht * 16 + l16] = o[ht][r] / l_run[r];
        }
    }
}

// ---------------------------------------------------------------------------
extern "C" void kernel_launch(void* const* d_in, const int* in_sizes, int n_in,
                              void* d_out, int out_size, void* d_ws, size_t ws_size,
                              hipStream_t stream) {
    const float* x  = (const float*)d_in[0];
    const float* Wq = (const float*)d_in[1];
    const float* Wk = (const float*)d_in[2];
    const float* Wv = (const float*)d_in[3];
    float* out = (float*)d_out;

    // workspace layout (bf16 halves): Qb | Kb | VTb | Wt  => ~6.4 MB total
    unsigned short* Qb  = (unsigned short*)d_ws;
    unsigned short* Kb  = Qb  + (size_t)B_ * T_ * H_;
    unsigned short* VTb = Kb  + (size_t)B_ * T_ * H_;
    unsigned short* Wt  = VTb + (size_t)B_ * T_ * H_;

    cast_weights<<<(3 * C_ * H_) / 256, 256, 0, stream>>>(Wq, Wk, Wv, Wt);
    qkv_proj<<<(B_ * T_) / 64, 256, 0, stream>>>(x, Wt, Qb, Kb, VTb);
    attn<<<B_ * (T_ / 64), 256, 0, stream>>>(Qb, Kb, VTb, out);
}

// Round 2
// 231.991 us; speedup vs baseline: 1.0589x; 1.0589x over previous
//
#include <hip/hip_runtime.h>

// Problem constants (reference: B=8, T=2048, C=1024, H=64)
#define B_ 8
#define T_ 2048
#define C_ 1024
#define H_ 64

typedef __bf16 bf16x8 __attribute__((ext_vector_type(8)));
typedef float  f32x4  __attribute__((ext_vector_type(4)));
typedef unsigned short u16x8 __attribute__((ext_vector_type(8)));

// round-half-up f32 -> bf16 bits
__device__ __forceinline__ unsigned short f2bf(float f) {
    unsigned u = __builtin_bit_cast(unsigned, f);
    u += 0x8000u;
    return (unsigned short)(u >> 16);
}

__device__ __forceinline__ unsigned pack2(float lo, float hi) {
    unsigned a = __builtin_bit_cast(unsigned, lo) + 0x8000u;
    unsigned b = __builtin_bit_cast(unsigned, hi) + 0x8000u;
    return (a >> 16) | (b & 0xffff0000u);
}

union U8 { unsigned u32[4]; u16x8 v; };

__device__ __forceinline__ bf16x8 load8_cvt(const float* p) {
    float4 f0 = *(const float4*)p;
    float4 f1 = *(const float4*)(p + 4);
    U8 r;
    r.u32[0] = pack2(f0.x, f0.y);
    r.u32[1] = pack2(f0.z, f0.w);
    r.u32[2] = pack2(f1.x, f1.y);
    r.u32[3] = pack2(f1.z, f1.w);
    return __builtin_bit_cast(bf16x8, r.v);
}

__device__ __forceinline__ bf16x8 load8_bf(const unsigned short* p) {
    return __builtin_bit_cast(bf16x8, *(const u16x8*)p);
}

// ---------------------------------------------------------------------------
// Kernel 0: pack Wq,Wk,Wv (fp32 [C][H]) into transposed bf16 Wt[192][C].
// ---------------------------------------------------------------------------
__global__ void cast_weights(const float* __restrict__ Wq,
                             const float* __restrict__ Wk,
                             const float* __restrict__ Wv,
                             unsigned short* __restrict__ Wt) {
    int idx = blockIdx.x * blockDim.x + threadIdx.x;
    int w   = idx >> 16;            // / (C*H) = 65536
    int rem = idx & 0xffff;
    int c   = rem & (C_ - 1);       // fastest -> coalesced Wt writes
    int h   = rem >> 10;
    const float* W = (w == 0) ? Wq : (w == 1) ? Wk : Wv;
    Wt[(size_t)(w * H_ + h) * C_ + c] = f2bf(W[(size_t)c * H_ + h]);
}

// ---------------------------------------------------------------------------
// Kernel 1: fused QKV projection, v2 (occupancy fix).
// Grid = B*T/16 = 1024 blocks x 256 threads.  Block = 16 rows of x.
// All 4 waves read the SAME 16 x-rows (L1-shared); wave w computes n-tiles
// 3w..3w+2 of the 12 (Q:0-3, K:4-7, V:8-11).  16 waves/CU vs v1's 4.
// ---------------------------------------------------------------------------
__global__ __launch_bounds__(256) void qkv_proj(
        const float* __restrict__ x,
        const unsigned short* __restrict__ Wt,
        unsigned short* __restrict__ Qb,
        unsigned short* __restrict__ Kb,
        unsigned short* __restrict__ VTb) {
    const int tid  = threadIdx.x;
    const int wave = tid >> 6;
    const int lane = tid & 63;
    const int l16  = lane & 15;
    const int quad = lane >> 4;
    const size_t r0 = (size_t)blockIdx.x * 16;

    const float* xrow = x + (r0 + l16) * C_ + quad * 8;
    const int nt0 = wave * 3;

    f32x4 acc[3];
#pragma unroll
    for (int i = 0; i < 3; i++) acc[i] = (f32x4){0.f, 0.f, 0.f, 0.f};

    for (int k0 = 0; k0 < C_; k0 += 64) {
        bf16x8 a0 = load8_cvt(xrow + k0);
        bf16x8 a1 = load8_cvt(xrow + k0 + 32);
#pragma unroll
        for (int i = 0; i < 3; i++) {
            const unsigned short* brow =
                Wt + (size_t)((nt0 + i) * 16 + l16) * C_ + k0 + quad * 8;
            bf16x8 b0 = load8_bf(brow);
            bf16x8 b1 = load8_bf(brow + 32);
            acc[i] = __builtin_amdgcn_mfma_f32_16x16x32_bf16(a0, b0, acc[i], 0, 0, 0);
            acc[i] = __builtin_amdgcn_mfma_f32_16x16x32_bf16(a1, b1, acc[i], 0, 0, 0);
        }
    }

    // epilogue: C/D layout col=l16, row=quad*4+reg
    const int mrow_base = (int)r0 + quad * 4;
#pragma unroll
    for (int i = 0; i < 3; i++) {
        int nt = nt0 + i;
#pragma unroll
        for (int r = 0; r < 4; r++) {
            int row = mrow_base + r;
            unsigned short bv = f2bf(acc[i][r]);
            if (nt < 4) {
                Qb[(size_t)row * H_ + nt * 16 + l16] = bv;
            } else if (nt < 8) {
                Kb[(size_t)row * H_ + (nt - 4) * 16 + l16] = bv;
            } else {
                int h = (nt - 8) * 16 + l16;
                int b = row >> 11;
                int t = row & (T_ - 1);
                VTb[((size_t)b * H_ + h) * T_ + t] = bv;
            }
        }
    }
}

// ---------------------------------------------------------------------------
// Kernel 2: flash attention, v2 (occupancy fix).
// Grid = B * T/16 = 1024 single-wave blocks.  Each wave owns 16 q-rows and
// iterates its whole causal KV range in 64-key tiles.  K and V^T fragments
// are read DIRECTLY from global (L2-resident: KV = 4MB total) — no staging
// LDS, no __syncthreads.  LDS only for the wave-private P C->A layout
// round-trip.  ~16 waves/CU vs v1's ~2, and no triangular block imbalance
// beyond grid-level scheduling (1024 blocks / 256 CUs smooths it).
// ---------------------------------------------------------------------------
#define ASTRIDE 72

__global__ __launch_bounds__(64) void attn(
        const unsigned short* __restrict__ Qb,
        const unsigned short* __restrict__ Kb,
        const unsigned short* __restrict__ VTb,
        float* __restrict__ out) {
    __shared__ __attribute__((aligned(16))) unsigned short ps_[16 * ASTRIDE];

    const int lane = threadIdx.x & 63;
    const int l16  = lane & 15;
    const int quad = lane >> 4;
    const int b    = blockIdx.x >> 7;     // / (T/16)
    const int qt   = blockIdx.x & 127;
    const int q0   = qt * 16;
    const int tdiag = qt >> 2;            // diagonal 64-key tile index

    // Q fragments: A[m=l16][k=quad*8+j], rows q0+l16, held in registers
    const unsigned short* qrow =
        Qb + ((size_t)b * T_ + q0 + l16) * H_ + quad * 8;
    bf16x8 qf0 = load8_bf(qrow);
    bf16x8 qf1 = load8_bf(qrow + 32);

    f32x4 o[4];
#pragma unroll
    for (int i = 0; i < 4; i++) o[i] = (f32x4){0.f, 0.f, 0.f, 0.f};
    float m_run[4], l_run[4];
#pragma unroll
    for (int r = 0; r < 4; r++) { m_run[r] = -1e30f; l_run[r] = 0.f; }

    const float scale = 0.125f;  // 1/sqrt(H)
    const unsigned short* Kbase = Kb + (size_t)b * T_ * H_;
    const unsigned short* Vbase = VTb + (size_t)b * H_ * T_;

    for (int t = 0; t <= tdiag; t++) {
        // S = Q K^T : K fragments straight from global
        f32x4 s[4];
#pragma unroll
        for (int nt = 0; nt < 4; nt++) {
            const unsigned short* krow =
                Kbase + (size_t)(t * 64 + nt * 16 + l16) * H_ + quad * 8;
            bf16x8 kf0 = load8_bf(krow);
            bf16x8 kf1 = load8_bf(krow + 32);
            f32x4 z = (f32x4){0.f, 0.f, 0.f, 0.f};
            z = __builtin_amdgcn_mfma_f32_16x16x32_bf16(qf0, kf0, z, 0, 0, 0);
            z = __builtin_amdgcn_mfma_f32_16x16x32_bf16(qf1, kf1, z, 0, 0, 0);
            s[nt] = z;
        }

#pragma unroll
        for (int nt = 0; nt < 4; nt++)
#pragma unroll
            for (int r = 0; r < 4; r++) s[nt][r] *= scale;

        if (t == tdiag) {   // causal mask on the diagonal tile only
#pragma unroll
            for (int nt = 0; nt < 4; nt++) {
                int key = t * 64 + nt * 16 + l16;
#pragma unroll
                for (int r = 0; r < 4; r++) {
                    int q = q0 + quad * 4 + r;
                    if (key > q) s[nt][r] = -1e30f;
                }
            }
        }

        // online softmax: row max over 64 cols (16-lane reduce within quad)
        float alpha[4];
#pragma unroll
        for (int r = 0; r < 4; r++) {
            float v = fmaxf(fmaxf(s[0][r], s[1][r]), fmaxf(s[2][r], s[3][r]));
            v = fmaxf(v, __shfl_xor(v, 1));
            v = fmaxf(v, __shfl_xor(v, 2));
            v = fmaxf(v, __shfl_xor(v, 4));
            v = fmaxf(v, __shfl_xor(v, 8));
            float m_new = fmaxf(m_run[r], v);
            alpha[r] = __expf(m_run[r] - m_new);
            m_run[r] = m_new;
        }

        float rsum[4] = {0.f, 0.f, 0.f, 0.f};
#pragma unroll
        for (int nt = 0; nt < 4; nt++) {
#pragma unroll
            for (int r = 0; r < 4; r++) {
                float p = __expf(s[nt][r] - m_run[r]);
                rsum[r] += p;
                ps_[(quad * 4 + r) * ASTRIDE + nt * 16 + l16] = f2bf(p);
            }
        }
#pragma unroll
        for (int r = 0; r < 4; r++) {
            float v = rsum[r];
            v += __shfl_xor(v, 1);
            v += __shfl_xor(v, 2);
            v += __shfl_xor(v, 4);
            v += __shfl_xor(v, 8);
            l_run[r] = l_run[r] * alpha[r] + v;
        }

#pragma unroll
        for (int ht = 0; ht < 4; ht++)
#pragma unroll
            for (int r = 0; r < 4; r++) o[ht][r] *= alpha[r];

        // PV: A = P (LDS round-trip -> A layout), B = V^T rows from global
#pragma unroll
        for (int ks = 0; ks < 2; ks++) {
            bf16x8 pf = load8_bf(&ps_[l16 * ASTRIDE + ks * 32 + quad * 8]);
#pragma unroll
            for (int ht = 0; ht < 4; ht++) {
                const unsigned short* vrow =
                    Vbase + (size_t)(ht * 16 + l16) * T_ + t * 64 + ks * 32 + quad * 8;
                bf16x8 vf = load8_bf(vrow);
                o[ht] = __builtin_amdgcn_mfma_f32_16x16x32_bf16(pf, vf, o[ht], 0, 0, 0);
            }
        }
    }

    // epilogue: out fp32 [B][T][H]
#pragma unroll
    for (int ht = 0; ht < 4; ht++) {
#pragma unroll
        for (int r = 0; r < 4; r++) {
            int t = q0 + quad * 4 + r;
            out[((size_t)b * T_ + t) * H_ + ht * 16 + l16] = o[ht][r] / l_run[r];
        }
    }
}

// ---------------------------------------------------------------------------
extern "C" void kernel_launch(void* const* d_in, const int* in_sizes, int n_in,
                              void* d_out, int out_size, void* d_ws, size_t ws_size,
                              hipStream_t stream) {
    const float* x  = (const float*)d_in[0];
    const float* Wq = (const float*)d_in[1];
    const float* Wk = (const float*)d_in[2];
    const float* Wv = (const float*)d_in[3];
    float* out = (float*)d_out;

    unsigned short* Qb  = (unsigned short*)d_ws;
    unsigned short* Kb  = Qb  + (size_t)B_ * T_ * H_;
    unsigned short* VTb = Kb  + (size_t)B_ * T_ * H_;
    unsigned short* Wt  = VTb + (size_t)B_ * T_ * H_;

    cast_weights<<<(3 * C_ * H_) / 256, 256, 0, stream>>>(Wq, Wk, Wv, Wt);
    qkv_proj<<<(B_ * T_) / 16, 256, 0, stream>>>(x, Wt, Qb, Kb, VTb);
    attn<<<B_ * (T_ / 16), 64, 0, stream>>>(Qb, Kb, VTb, out);
}

// Round 3
// 222.599 us; speedup vs baseline: 1.1036x; 1.0422x over previous
//
#include <hip/hip_runtime.h>

// Problem constants (reference: B=8, T=2048, C=1024, H=64)
#define B_ 8
#define T_ 2048
#define C_ 1024
#define H_ 64

typedef __bf16 bf16x8 __attribute__((ext_vector_type(8)));
typedef float  f32x4  __attribute__((ext_vector_type(4)));
typedef unsigned short u16x8 __attribute__((ext_vector_type(8)));

// round-half-up f32 -> bf16 bits
__device__ __forceinline__ unsigned short f2bf(float f) {
    unsigned u = __builtin_bit_cast(unsigned, f);
    u += 0x8000u;
    return (unsigned short)(u >> 16);
}

__device__ __forceinline__ unsigned pack2(float lo, float hi) {
    unsigned a = __builtin_bit_cast(unsigned, lo) + 0x8000u;
    unsigned b = __builtin_bit_cast(unsigned, hi) + 0x8000u;
    return (a >> 16) | (b & 0xffff0000u);
}

union U8 { unsigned u32[4]; u16x8 v; };

__device__ __forceinline__ bf16x8 load8_cvt(const float* p) {
    float4 f0 = *(const float4*)p;
    float4 f1 = *(const float4*)(p + 4);
    U8 r;
    r.u32[0] = pack2(f0.x, f0.y);
    r.u32[1] = pack2(f0.z, f0.w);
    r.u32[2] = pack2(f1.x, f1.y);
    r.u32[3] = pack2(f1.z, f1.w);
    return __builtin_bit_cast(bf16x8, r.v);
}

__device__ __forceinline__ bf16x8 load8_bf(const unsigned short* p) {
    return __builtin_bit_cast(bf16x8, *(const u16x8*)p);
}

// ---------------------------------------------------------------------------
// Kernel 0: pack Wq,Wk,Wv (fp32 [C][H]) into transposed bf16 Wt[192][C].
// ---------------------------------------------------------------------------
__global__ void cast_weights(const float* __restrict__ Wq,
                             const float* __restrict__ Wk,
                             const float* __restrict__ Wv,
                             unsigned short* __restrict__ Wt) {
    int idx = blockIdx.x * blockDim.x + threadIdx.x;
    int w   = idx >> 16;            // / (C*H) = 65536
    int rem = idx & 0xffff;
    int c   = rem & (C_ - 1);       // fastest -> coalesced Wt writes
    int h   = rem >> 10;
    const float* W = (w == 0) ? Wq : (w == 1) ? Wk : Wv;
    Wt[(size_t)(w * H_ + h) * C_ + c] = f2bf(W[(size_t)c * H_ + h]);
}

// ---------------------------------------------------------------------------
// Kernel 1: fused QKV projection, v3 (split-K + prefetch).
// Grid = B*T/16 = 1024 blocks x 512 threads (8 waves = 32 waves/CU at 4
// blocks/CU).  Block = 16 rows of x.  Wave w: k-half = w>>2, n-tiles
// 3*(w&3)..+2 of 12 (Q:0-3, K:4-7, V:8-11).  Waves 4-7 store fp32 partials
// to LDS; waves 0-3 add and write bf16 outputs.  x-fragments are prefetched
// one k-step ahead so the LLC load latency overlaps the 6 MFMAs.
// ---------------------------------------------------------------------------
__global__ __launch_bounds__(512) void qkv_proj(
        const float* __restrict__ x,
        const unsigned short* __restrict__ Wt,
        unsigned short* __restrict__ Qb,
        unsigned short* __restrict__ Kb,
        unsigned short* __restrict__ VTb) {
    // element-major reduction buffer: red_[elem][upper_wave][lane] -> no conflicts
    __shared__ float red_[12 * 4 * 64];

    const int tid   = threadIdx.x;
    const int wave  = tid >> 6;          // 0..7
    const int lane  = tid & 63;
    const int l16   = lane & 15;
    const int quad  = lane >> 4;
    const int khalf = wave >> 2;         // 0 or 1
    const int nt0   = (wave & 3) * 3;
    const size_t r0 = (size_t)blockIdx.x * 16;

    const float* xrow = x + (r0 + l16) * C_ + khalf * 512 + quad * 8;
    const int kbase = khalf * 512;

    f32x4 acc[3];
#pragma unroll
    for (int i = 0; i < 3; i++) acc[i] = (f32x4){0.f, 0.f, 0.f, 0.f};

    bf16x8 a0 = load8_cvt(xrow);
    bf16x8 a1 = load8_cvt(xrow + 32);
    for (int k0 = 0; k0 < 512; k0 += 64) {
        bf16x8 na0 = a0, na1 = a1;
        if (k0 < 448) {                      // prefetch next k-step
            na0 = load8_cvt(xrow + k0 + 64);
            na1 = load8_cvt(xrow + k0 + 96);
        }
#pragma unroll
        for (int i = 0; i < 3; i++) {
            const unsigned short* brow =
                Wt + (size_t)((nt0 + i) * 16 + l16) * C_ + kbase + k0 + quad * 8;
            bf16x8 b0 = load8_bf(brow);
            bf16x8 b1 = load8_bf(brow + 32);
            acc[i] = __builtin_amdgcn_mfma_f32_16x16x32_bf16(a0, b0, acc[i], 0, 0, 0);
            acc[i] = __builtin_amdgcn_mfma_f32_16x16x32_bf16(a1, b1, acc[i], 0, 0, 0);
        }
        a0 = na0; a1 = na1;
    }

    // cross-wave k-merge: upper waves deposit, lower waves add + epilogue
    if (wave >= 4) {
#pragma unroll
        for (int i = 0; i < 3; i++)
#pragma unroll
            for (int r = 0; r < 4; r++)
                red_[(i * 4 + r) * 256 + (wave - 4) * 64 + lane] = acc[i][r];
    }
    __syncthreads();
    if (wave < 4) {
        const int mrow_base = (int)r0 + quad * 4;
#pragma unroll
        for (int i = 0; i < 3; i++) {
            int nt = nt0 + i;
#pragma unroll
            for (int r = 0; r < 4; r++) {
                float v = acc[i][r] + red_[(i * 4 + r) * 256 + wave * 64 + lane];
                int row = mrow_base + r;
                unsigned short bv = f2bf(v);
                if (nt < 4) {
                    Qb[(size_t)row * H_ + nt * 16 + l16] = bv;
                } else if (nt < 8) {
                    Kb[(size_t)row * H_ + (nt - 4) * 16 + l16] = bv;
                } else {
                    int h = (nt - 8) * 16 + l16;
                    int b = row >> 11;
                    int t = row & (T_ - 1);
                    VTb[((size_t)b * H_ + h) * T_ + t] = bv;
                }
            }
        }
    }
}

// ---------------------------------------------------------------------------
// Kernel 2: flash attention, v3 (KV-split x4 + LSE merge).
// Grid = B * T/16 = 1024 blocks x 256 threads.  Block = 16 q-rows; wave s
// processes KV tiles t = s, s+4, ... <= tdiag (interleaved -> balanced),
// keeping its own online-softmax state.  Partial (m, l, O) merged across the
// 4 waves in LDS at the end.  Longest serial chain drops 32 -> 8 tiles, and
// waves/CU goes 4 -> 16.
// ---------------------------------------------------------------------------
#define ASTRIDE 72
#define OMSTRIDE 65   // fp32 merge-buffer row stride (2-way max bank aliasing)

__global__ __launch_bounds__(256) void attn(
        const unsigned short* __restrict__ Qb,
        const unsigned short* __restrict__ Kb,
        const unsigned short* __restrict__ VTb,
        float* __restrict__ out) {
    __shared__ __attribute__((aligned(16))) unsigned short ps_[4 * 16 * ASTRIDE];
    __shared__ float Om_[4 * 16 * OMSTRIDE];
    __shared__ float ml0_[4][16];
    __shared__ float ml1_[4][16];

    const int tid  = threadIdx.x;
    const int wave = tid >> 6;            // KV-split index s = 0..3
    const int lane = tid & 63;
    const int l16  = lane & 15;
    const int quad = lane >> 4;
    const int b    = blockIdx.x >> 7;     // / (T/16)
    const int qt   = blockIdx.x & 127;
    const int q0   = qt * 16;
    const int tdiag = qt >> 2;            // diagonal 64-key tile index

    // Q fragments: A[m=l16][k=quad*8+j], rows q0+l16 (same for all 4 waves)
    const unsigned short* qrow =
        Qb + ((size_t)b * T_ + q0 + l16) * H_ + quad * 8;
    bf16x8 qf0 = load8_bf(qrow);
    bf16x8 qf1 = load8_bf(qrow + 32);

    f32x4 o[4];
#pragma unroll
    for (int i = 0; i < 4; i++) o[i] = (f32x4){0.f, 0.f, 0.f, 0.f};
    float m_run[4], l_run[4];
#pragma unroll
    for (int r = 0; r < 4; r++) { m_run[r] = -1e30f; l_run[r] = 0.f; }

    const float scale = 0.125f;  // 1/sqrt(H)
    const unsigned short* Kbase = Kb + (size_t)b * T_ * H_;
    const unsigned short* Vbase = VTb + (size_t)b * H_ * T_;
    unsigned short* psw = &ps_[wave * 16 * ASTRIDE];

    for (int t = wave; t <= tdiag; t += 4) {
        // S = Q K^T : K fragments straight from global (L2-resident)
        f32x4 s[4];
#pragma unroll
        for (int nt = 0; nt < 4; nt++) {
            const unsigned short* krow =
                Kbase + (size_t)(t * 64 + nt * 16 + l16) * H_ + quad * 8;
            bf16x8 kf0 = load8_bf(krow);
            bf16x8 kf1 = load8_bf(krow + 32);
            f32x4 z = (f32x4){0.f, 0.f, 0.f, 0.f};
            z = __builtin_amdgcn_mfma_f32_16x16x32_bf16(qf0, kf0, z, 0, 0, 0);
            z = __builtin_amdgcn_mfma_f32_16x16x32_bf16(qf1, kf1, z, 0, 0, 0);
            s[nt] = z;
        }

#pragma unroll
        for (int nt = 0; nt < 4; nt++)
#pragma unroll
            for (int r = 0; r < 4; r++) s[nt][r] *= scale;

        if (t == tdiag) {   // causal mask on the diagonal tile only
#pragma unroll
            for (int nt = 0; nt < 4; nt++) {
                int key = t * 64 + nt * 16 + l16;
#pragma unroll
                for (int r = 0; r < 4; r++) {
                    int q = q0 + quad * 4 + r;
                    if (key > q) s[nt][r] = -1e30f;
                }
            }
        }

        // online softmax: row max over 64 cols (16-lane reduce within quad)
        float alpha[4];
#pragma unroll
        for (int r = 0; r < 4; r++) {
            float v = fmaxf(fmaxf(s[0][r], s[1][r]), fmaxf(s[2][r], s[3][r]));
            v = fmaxf(v, __shfl_xor(v, 1));
            v = fmaxf(v, __shfl_xor(v, 2));
            v = fmaxf(v, __shfl_xor(v, 4));
            v = fmaxf(v, __shfl_xor(v, 8));
            float m_new = fmaxf(m_run[r], v);
            alpha[r] = __expf(m_run[r] - m_new);
            m_run[r] = m_new;
        }

        float rsum[4] = {0.f, 0.f, 0.f, 0.f};
#pragma unroll
        for (int nt = 0; nt < 4; nt++) {
#pragma unroll
            for (int r = 0; r < 4; r++) {
                float p = __expf(s[nt][r] - m_run[r]);
                rsum[r] += p;
                psw[(quad * 4 + r) * ASTRIDE + nt * 16 + l16] = f2bf(p);
            }
        }
#pragma unroll
        for (int r = 0; r < 4; r++) {
            float v = rsum[r];
            v += __shfl_xor(v, 1);
            v += __shfl_xor(v, 2);
            v += __shfl_xor(v, 4);
            v += __shfl_xor(v, 8);
            l_run[r] = l_run[r] * alpha[r] + v;
        }

#pragma unroll
        for (int ht = 0; ht < 4; ht++)
#pragma unroll
            for (int r = 0; r < 4; r++) o[ht][r] *= alpha[r];

        // PV: A = P (LDS round-trip -> A layout), B = V^T rows from global
#pragma unroll
        for (int ks = 0; ks < 2; ks++) {
            bf16x8 pf = load8_bf(&psw[l16 * ASTRIDE + ks * 32 + quad * 8]);
#pragma unroll
            for (int ht = 0; ht < 4; ht++) {
                const unsigned short* vrow =
                    Vbase + (size_t)(ht * 16 + l16) * T_ + t * 64 + ks * 32 + quad * 8;
                bf16x8 vf = load8_bf(vrow);
                o[ht] = __builtin_amdgcn_mfma_f32_16x16x32_bf16(pf, vf, o[ht], 0, 0, 0);
            }
        }
    }

    // ---- cross-wave LSE merge ----
    // deposit partial state: O rows=quad*4+r cols=ht*16+l16; m,l per row
#pragma unroll
    for (int ht = 0; ht < 4; ht++)
#pragma unroll
        for (int r = 0; r < 4; r++)
            Om_[(wave * 16 + quad * 4 + r) * OMSTRIDE + ht * 16 + l16] = o[ht][r];
    if (l16 == 0) {
#pragma unroll
        for (int r = 0; r < 4; r++) {
            ml0_[wave][quad * 4 + r] = m_run[r];
            ml1_[wave][quad * 4 + r] = l_run[r];
        }
    }
    __syncthreads();

    // wave s finalizes output columns [s*16, s*16+16)
    const int col = wave * 16 + l16;
#pragma unroll
    for (int r = 0; r < 4; r++) {
        int row = quad * 4 + r;
        float m0 = ml0_[0][row], m1 = ml0_[1][row];
        float m2 = ml0_[2][row], m3 = ml0_[3][row];
        float mM = fmaxf(fmaxf(m0, m1), fmaxf(m2, m3));
        float e0 = __expf(m0 - mM), e1 = __expf(m1 - mM);
        float e2 = __expf(m2 - mM), e3 = __expf(m3 - mM);
        float lsum = e0 * ml1_[0][row] + e1 * ml1_[1][row]
                   + e2 * ml1_[2][row] + e3 * ml1_[3][row];
        float ov = e0 * Om_[(0 * 16 + row) * OMSTRIDE + col]
                 + e1 * Om_[(1 * 16 + row) * OMSTRIDE + col]
                 + e2 * Om_[(2 * 16 + row) * OMSTRIDE + col]
                 + e3 * Om_[(3 * 16 + row) * OMSTRIDE + col];
        out[((size_t)b * T_ + q0 + row) * H_ + col] = ov / lsum;
    }
}

// ---------------------------------------------------------------------------
extern "C" void kernel_launch(void* const* d_in, const int* in_sizes, int n_in,
                              void* d_out, int out_size, void* d_ws, size_t ws_size,
                              hipStream_t stream) {
    const float* x  = (const float*)d_in[0];
    const float* Wq = (const float*)d_in[1];
    const float* Wk = (const float*)d_in[2];
    const float* Wv = (const float*)d_in[3];
    float* out = (float*)d_out;

    unsigned short* Qb  = (unsigned short*)d_ws;
    unsigned short* Kb  = Qb  + (size_t)B_ * T_ * H_;
    unsigned short* VTb = Kb  + (size_t)B_ * T_ * H_;
    unsigned short* Wt  = VTb + (size_t)B_ * T_ * H_;

    cast_weights<<<(3 * C_ * H_) / 256, 256, 0, stream>>>(Wq, Wk, Wv, Wt);
    qkv_proj<<<(B_ * T_) / 16, 512, 0, stream>>>(x, Wt, Qb, Kb, VTb);
    attn<<<B_ * (T_ / 16), 256, 0, stream>>>(Qb, Kb, VTb, out);
}

// Round 4
// 177.871 us; speedup vs baseline: 1.3811x; 1.2515x over previous
//
#include <hip/hip_runtime.h>

// Problem constants (reference: B=8, T=2048, C=1024, H=64)
#define B_ 8
#define T_ 2048
#define C_ 1024
#define H_ 64

typedef __bf16 bf16x8 __attribute__((ext_vector_type(8)));
typedef float  f32x4  __attribute__((ext_vector_type(4)));
typedef unsigned short u16x8 __attribute__((ext_vector_type(8)));

// round-half-up f32 -> bf16 bits
__device__ __forceinline__ unsigned short f2bf(float f) {
    unsigned u = __builtin_bit_cast(unsigned, f);
    u += 0x8000u;
    return (unsigned short)(u >> 16);
}

__device__ __forceinline__ unsigned pack2(float lo, float hi) {
    unsigned a = __builtin_bit_cast(unsigned, lo) + 0x8000u;
    unsigned b = __builtin_bit_cast(unsigned, hi) + 0x8000u;
    return (a >> 16) | (b & 0xffff0000u);
}

union U8 { unsigned u32[4]; u16x8 v; };

__device__ __forceinline__ bf16x8 load8_bf(const unsigned short* p) {
    return __builtin_bit_cast(bf16x8, *(const u16x8*)p);
}

// ---------------------------------------------------------------------------
// Kernel 0: pack Wq,Wk,Wv (fp32 [C][H]) into transposed bf16 Wt[192][C].
// ---------------------------------------------------------------------------
__global__ void cast_weights(const float* __restrict__ Wq,
                             const float* __restrict__ Wk,
                             const float* __restrict__ Wv,
                             unsigned short* __restrict__ Wt) {
    int idx = blockIdx.x * blockDim.x + threadIdx.x;
    int w   = idx >> 16;            // / (C*H) = 65536
    int rem = idx & 0xffff;
    int c   = rem & (C_ - 1);       // fastest -> coalesced Wt writes
    int h   = rem >> 10;
    const float* W = (w == 0) ? Wq : (w == 1) ? Wk : Wv;
    Wt[(size_t)(w * H_ + h) * C_ + c] = f2bf(W[(size_t)c * H_ + h]);
}

// ---------------------------------------------------------------------------
// Kernel 1: fused QKV projection, v4 (LDS-staged GEMM, m97 structure).
// Grid = B*T/64 = 256 blocks x 512 threads.  Block = 64 rows x 192 cols,
// K-loop 16 steps of BK=64.  Per k-step: stage A (x fp32 -> bf16, dense
// coalesced) and B (Wt bf16, dense) into LDS with 16B-group XOR swizzle
// (g ^ (row&7): uniform bank use, 16B-aligned b128, no padding).  Waves read
// MFMA fragments with ds_read_b128.  Wave (ms=w>>1, nh=w&1) computes m-strip
// ms x n-tiles [6*nh, 6*nh+6).  This kills the 16-segment global gathers and
// the 384MB Wt re-read amplification of v3.
// ---------------------------------------------------------------------------
__global__ __launch_bounds__(512) void qkv_proj(
        const float* __restrict__ x,
        const unsigned short* __restrict__ Wt,
        unsigned short* __restrict__ Qb,
        unsigned short* __restrict__ Kb,
        unsigned short* __restrict__ VTb) {
    __shared__ __attribute__((aligned(16))) unsigned short As_[64 * 64];   // 8 KB
    __shared__ __attribute__((aligned(16))) unsigned short Bs_[192 * 64];  // 24 KB

    const int tid  = threadIdx.x;
    const int wave = tid >> 6;
    const int lane = tid & 63;
    const int l16  = lane & 15;
    const int quad = lane >> 4;
    const int ms   = wave >> 1;          // m-strip 0..3 (16 rows each)
    const int nh   = wave & 1;           // n-half: n-tiles 6*nh .. 6*nh+5
    const size_t r0 = (size_t)blockIdx.x * 64;

    // staging roles: A: thread -> (row sa_m, 16B-group sa_g), 64x8 groups
    const int sa_m = tid >> 3, sa_g = tid & 7;
    const float* sa_src = x + (r0 + sa_m) * C_ + sa_g * 8;
    unsigned short* sa_dst = &As_[sa_m * 64 + ((sa_g ^ (sa_m & 7)) * 8)];

    f32x4 acc[6];
#pragma unroll
    for (int i = 0; i < 6; i++) acc[i] = (f32x4){0.f, 0.f, 0.f, 0.f};

    const int sw = (l16 & 7);            // fragment-read swizzle key

    for (int k0 = 0; k0 < C_; k0 += 64) {
        __syncthreads();   // prior k-step's fragment reads done
        // ---- stage A: 64 rows x 64 k of x, fp32 -> bf16 ----
        {
            float4 f0 = *(const float4*)(sa_src + k0);
            float4 f1 = *(const float4*)(sa_src + k0 + 4);
            U8 rr;
            rr.u32[0] = pack2(f0.x, f0.y);
            rr.u32[1] = pack2(f0.z, f0.w);
            rr.u32[2] = pack2(f1.x, f1.y);
            rr.u32[3] = pack2(f1.z, f1.w);
            *(u16x8*)sa_dst = rr.v;
        }
        // ---- stage B: 192 rows x 64 k of Wt (bf16), 3 passes ----
#pragma unroll
        for (int p = 0; p < 3; p++) {
            int f   = p * 512 + tid;
            int row = f >> 3, g = f & 7;
            u16x8 v = *(const u16x8*)(Wt + (size_t)row * C_ + k0 + g * 8);
            *(u16x8*)(&Bs_[row * 64 + ((g ^ (row & 7)) * 8)]) = v;
        }
        __syncthreads();
        // ---- compute: fragments from LDS ----
        const int arow = ms * 16 + l16;
        bf16x8 a0 = load8_bf(&As_[arow * 64 + (((quad    ) ^ sw) * 8)]);
        bf16x8 a1 = load8_bf(&As_[arow * 64 + (((quad + 4) ^ sw) * 8)]);
#pragma unroll
        for (int i = 0; i < 6; i++) {
            int brow = (nh * 6 + i) * 16 + l16;
            bf16x8 b0 = load8_bf(&Bs_[brow * 64 + (((quad    ) ^ sw) * 8)]);
            bf16x8 b1 = load8_bf(&Bs_[brow * 64 + (((quad + 4) ^ sw) * 8)]);
            acc[i] = __builtin_amdgcn_mfma_f32_16x16x32_bf16(a0, b0, acc[i], 0, 0, 0);
            acc[i] = __builtin_amdgcn_mfma_f32_16x16x32_bf16(a1, b1, acc[i], 0, 0, 0);
        }
    }

    // epilogue: C/D layout col=l16, row=quad*4+reg
    const int mrow_base = (int)r0 + ms * 16 + quad * 4;
#pragma unroll
    for (int i = 0; i < 6; i++) {
        int nt = nh * 6 + i;
#pragma unroll
        for (int r = 0; r < 4; r++) {
            int row = mrow_base + r;
            unsigned short bv = f2bf(acc[i][r]);
            if (nt < 4) {
                Qb[(size_t)row * H_ + nt * 16 + l16] = bv;
            } else if (nt < 8) {
                Kb[(size_t)row * H_ + (nt - 4) * 16 + l16] = bv;
            } else {
                int h = (nt - 8) * 16 + l16;
                int b = row >> 11;
                int t = row & (T_ - 1);
                VTb[((size_t)b * H_ + h) * T_ + t] = bv;
            }
        }
    }
}

// ---------------------------------------------------------------------------
// Kernel 2: flash attention, v3 (KV-split x4 + LSE merge) — unchanged.
// ---------------------------------------------------------------------------
#define ASTRIDE 72
#define OMSTRIDE 65   // fp32 merge-buffer row stride

__global__ __launch_bounds__(256) void attn(
        const unsigned short* __restrict__ Qb,
        const unsigned short* __restrict__ Kb,
        const unsigned short* __restrict__ VTb,
        float* __restrict__ out) {
    __shared__ __attribute__((aligned(16))) unsigned short ps_[4 * 16 * ASTRIDE];
    __shared__ float Om_[4 * 16 * OMSTRIDE];
    __shared__ float ml0_[4][16];
    __shared__ float ml1_[4][16];

    const int tid  = threadIdx.x;
    const int wave = tid >> 6;            // KV-split index s = 0..3
    const int lane = tid & 63;
    const int l16  = lane & 15;
    const int quad = lane >> 4;
    const int b    = blockIdx.x >> 7;     // / (T/16)
    const int qt   = blockIdx.x & 127;
    const int q0   = qt * 16;
    const int tdiag = qt >> 2;            // diagonal 64-key tile index

    const unsigned short* qrow =
        Qb + ((size_t)b * T_ + q0 + l16) * H_ + quad * 8;
    bf16x8 qf0 = load8_bf(qrow);
    bf16x8 qf1 = load8_bf(qrow + 32);

    f32x4 o[4];
#pragma unroll
    for (int i = 0; i < 4; i++) o[i] = (f32x4){0.f, 0.f, 0.f, 0.f};
    float m_run[4], l_run[4];
#pragma unroll
    for (int r = 0; r < 4; r++) { m_run[r] = -1e30f; l_run[r] = 0.f; }

    const float scale = 0.125f;  // 1/sqrt(H)
    const unsigned short* Kbase = Kb + (size_t)b * T_ * H_;
    const unsigned short* Vbase = VTb + (size_t)b * H_ * T_;
    unsigned short* psw = &ps_[wave * 16 * ASTRIDE];

    for (int t = wave; t <= tdiag; t += 4) {
        f32x4 s[4];
#pragma unroll
        for (int nt = 0; nt < 4; nt++) {
            const unsigned short* krow =
                Kbase + (size_t)(t * 64 + nt * 16 + l16) * H_ + quad * 8;
            bf16x8 kf0 = load8_bf(krow);
            bf16x8 kf1 = load8_bf(krow + 32);
            f32x4 z = (f32x4){0.f, 0.f, 0.f, 0.f};
            z = __builtin_amdgcn_mfma_f32_16x16x32_bf16(qf0, kf0, z, 0, 0, 0);
            z = __builtin_amdgcn_mfma_f32_16x16x32_bf16(qf1, kf1, z, 0, 0, 0);
            s[nt] = z;
        }

#pragma unroll
        for (int nt = 0; nt < 4; nt++)
#pragma unroll
            for (int r = 0; r < 4; r++) s[nt][r] *= scale;

        if (t == tdiag) {
#pragma unroll
            for (int nt = 0; nt < 4; nt++) {
                int key = t * 64 + nt * 16 + l16;
#pragma unroll
                for (int r = 0; r < 4; r++) {
                    int q = q0 + quad * 4 + r;
                    if (key > q) s[nt][r] = -1e30f;
                }
            }
        }

        float alpha[4];
#pragma unroll
        for (int r = 0; r < 4; r++) {
            float v = fmaxf(fmaxf(s[0][r], s[1][r]), fmaxf(s[2][r], s[3][r]));
            v = fmaxf(v, __shfl_xor(v, 1));
            v = fmaxf(v, __shfl_xor(v, 2));
            v = fmaxf(v, __shfl_xor(v, 4));
            v = fmaxf(v, __shfl_xor(v, 8));
            float m_new = fmaxf(m_run[r], v);
            alpha[r] = __expf(m_run[r] - m_new);
            m_run[r] = m_new;
        }

        float rsum[4] = {0.f, 0.f, 0.f, 0.f};
#pragma unroll
        for (int nt = 0; nt < 4; nt++) {
#pragma unroll
            for (int r = 0; r < 4; r++) {
                float p = __expf(s[nt][r] - m_run[r]);
                rsum[r] += p;
                psw[(quad * 4 + r) * ASTRIDE + nt * 16 + l16] = f2bf(p);
            }
        }
#pragma unroll
        for (int r = 0; r < 4; r++) {
            float v = rsum[r];
            v += __shfl_xor(v, 1);
            v += __shfl_xor(v, 2);
            v += __shfl_xor(v, 4);
            v += __shfl_xor(v, 8);
            l_run[r] = l_run[r] * alpha[r] + v;
        }

#pragma unroll
        for (int ht = 0; ht < 4; ht++)
#pragma unroll
            for (int r = 0; r < 4; r++) o[ht][r] *= alpha[r];

#pragma unroll
        for (int ks = 0; ks < 2; ks++) {
            bf16x8 pf = load8_bf(&psw[l16 * ASTRIDE + ks * 32 + quad * 8]);
#pragma unroll
            for (int ht = 0; ht < 4; ht++) {
                const unsigned short* vrow =
                    Vbase + (size_t)(ht * 16 + l16) * T_ + t * 64 + ks * 32 + quad * 8;
                bf16x8 vf = load8_bf(vrow);
                o[ht] = __builtin_amdgcn_mfma_f32_16x16x32_bf16(pf, vf, o[ht], 0, 0, 0);
            }
        }
    }

    // ---- cross-wave LSE merge ----
#pragma unroll
    for (int ht = 0; ht < 4; ht++)
#pragma unroll
        for (int r = 0; r < 4; r++)
            Om_[(wave * 16 + quad * 4 + r) * OMSTRIDE + ht * 16 + l16] = o[ht][r];
    if (l16 == 0) {
#pragma unroll
        for (int r = 0; r < 4; r++) {
            ml0_[wave][quad * 4 + r] = m_run[r];
            ml1_[wave][quad * 4 + r] = l_run[r];
        }
    }
    __syncthreads();

    const int col = wave * 16 + l16;
#pragma unroll
    for (int r = 0; r < 4; r++) {
        int row = quad * 4 + r;
        float m0 = ml0_[0][row], m1 = ml0_[1][row];
        float m2 = ml0_[2][row], m3 = ml0_[3][row];
        float mM = fmaxf(fmaxf(m0, m1), fmaxf(m2, m3));
        float e0 = __expf(m0 - mM), e1 = __expf(m1 - mM);
        float e2 = __expf(m2 - mM), e3 = __expf(m3 - mM);
        float lsum = e0 * ml1_[0][row] + e1 * ml1_[1][row]
                   + e2 * ml1_[2][row] + e3 * ml1_[3][row];
        float ov = e0 * Om_[(0 * 16 + row) * OMSTRIDE + col]
                 + e1 * Om_[(1 * 16 + row) * OMSTRIDE + col]
                 + e2 * Om_[(2 * 16 + row) * OMSTRIDE + col]
                 + e3 * Om_[(3 * 16 + row) * OMSTRIDE + col];
        out[((size_t)b * T_ + q0 + row) * H_ + col] = ov / lsum;
    }
}

// ---------------------------------------------------------------------------
extern "C" void kernel_launch(void* const* d_in, const int* in_sizes, int n_in,
                              void* d_out, int out_size, void* d_ws, size_t ws_size,
                              hipStream_t stream) {
    const float* x  = (const float*)d_in[0];
    const float* Wq = (const float*)d_in[1];
    const float* Wk = (const float*)d_in[2];
    const float* Wv = (const float*)d_in[3];
    float* out = (float*)d_out;

    unsigned short* Qb  = (unsigned short*)d_ws;
    unsigned short* Kb  = Qb  + (size_t)B_ * T_ * H_;
    unsigned short* VTb = Kb  + (size_t)B_ * T_ * H_;
    unsigned short* Wt  = VTb + (size_t)B_ * T_ * H_;

    cast_weights<<<(3 * C_ * H_) / 256, 256, 0, stream>>>(Wq, Wk, Wv, Wt);
    qkv_proj<<<(B_ * T_) / 64, 512, 0, stream>>>(x, Wt, Qb, Kb, VTb);
    attn<<<B_ * (T_ / 16), 256, 0, stream>>>(Qb, Kb, VTb, out);
}

// Round 5
// 163.707 us; speedup vs baseline: 1.5006x; 1.0865x over previous
//
#include <hip/hip_runtime.h>

// Problem constants (reference: B=8, T=2048, C=1024, H=64)
#define B_ 8
#define T_ 2048
#define C_ 1024
#define H_ 64

typedef __bf16 bf16x8 __attribute__((ext_vector_type(8)));
typedef float  f32x4  __attribute__((ext_vector_type(4)));
typedef unsigned short u16x8 __attribute__((ext_vector_type(8)));

// round-half-up f32 -> bf16 bits
__device__ __forceinline__ unsigned short f2bf(float f) {
    unsigned u = __builtin_bit_cast(unsigned, f);
    u += 0x8000u;
    return (unsigned short)(u >> 16);
}

__device__ __forceinline__ unsigned pack2(float lo, float hi) {
    unsigned a = __builtin_bit_cast(unsigned, lo) + 0x8000u;
    unsigned b = __builtin_bit_cast(unsigned, hi) + 0x8000u;
    return (a >> 16) | (b & 0xffff0000u);
}

union U8 { unsigned u32[4]; u16x8 v; };

__device__ __forceinline__ u16x8 cvt8(float4 f0, float4 f1) {
    U8 r;
    r.u32[0] = pack2(f0.x, f0.y);
    r.u32[1] = pack2(f0.z, f0.w);
    r.u32[2] = pack2(f1.x, f1.y);
    r.u32[3] = pack2(f1.z, f1.w);
    return r.v;
}

__device__ __forceinline__ bf16x8 load8_bf(const unsigned short* p) {
    return __builtin_bit_cast(bf16x8, *(const u16x8*)p);
}

// ---------------------------------------------------------------------------
// Kernel 0: pack Wq,Wk,Wv (fp32 [C][H]) into transposed bf16 Wt[192][C].
// ---------------------------------------------------------------------------
__global__ void cast_weights(const float* __restrict__ Wq,
                             const float* __restrict__ Wk,
                             const float* __restrict__ Wv,
                             unsigned short* __restrict__ Wt) {
    int idx = blockIdx.x * blockDim.x + threadIdx.x;
    int w   = idx >> 16;            // / (C*H) = 65536
    int rem = idx & 0xffff;
    int c   = rem & (C_ - 1);       // fastest -> coalesced Wt writes
    int h   = rem >> 10;
    const float* W = (w == 0) ? Wq : (w == 1) ? Wk : Wv;
    Wt[(size_t)(w * H_ + h) * C_ + c] = f2bf(W[(size_t)c * H_ + h]);
}

// ---------------------------------------------------------------------------
// Kernel 1: fused QKV projection, v5 (double-buffered LDS staging).
// Grid = 256 blocks x 512 threads (1 block/CU).  v4's two barriers per k-step
// serialized stage<->compute; v5 loads tile k+1 into VGPRs at loop top,
// computes tile k from buf^cur, stores k+1 into buf^nxt, ONE barrier.  Loads
// overlap the whole compute phase.  XOR-swizzled LDS layout as v4.
// ---------------------------------------------------------------------------
#define ABUF (64 * 64)
#define BBUF (192 * 64)

__global__ __launch_bounds__(512) void qkv_proj(
        const float* __restrict__ x,
        const unsigned short* __restrict__ Wt,
        unsigned short* __restrict__ Qb,
        unsigned short* __restrict__ Kb,
        unsigned short* __restrict__ VTb) {
    __shared__ __attribute__((aligned(16))) unsigned short As_[2 * ABUF];  // 16 KB
    __shared__ __attribute__((aligned(16))) unsigned short Bs_[2 * BBUF];  // 48 KB

    const int tid  = threadIdx.x;
    const int wave = tid >> 6;
    const int lane = tid & 63;
    const int l16  = lane & 15;
    const int quad = lane >> 4;
    const int ms   = wave >> 1;          // m-strip 0..3
    const int nh   = wave & 1;           // n-half
    const size_t r0 = (size_t)blockIdx.x * 64;

    // staging role: thread -> (row sa_m, 16B-group sa_g)
    const int sa_m = tid >> 3, sa_g = tid & 7;
    const float* sa_src = x + (r0 + sa_m) * C_ + sa_g * 8;
    const int sa_off = sa_m * 64 + ((sa_g ^ (sa_m & 7)) * 8);   // swizzled LDS offset
    // B: row p*64+sa_m, same group; dst offset = p*4096 + sa_off

    f32x4 acc[6];
#pragma unroll
    for (int i = 0; i < 6; i++) acc[i] = (f32x4){0.f, 0.f, 0.f, 0.f};

    const int sw = l16 & 7;

    // prologue: stage k-step 0 into buf 0
    {
        float4 f0 = *(const float4*)(sa_src);
        float4 f1 = *(const float4*)(sa_src + 4);
        *(u16x8*)(&As_[sa_off]) = cvt8(f0, f1);
#pragma unroll
        for (int p = 0; p < 3; p++) {
            u16x8 v = *(const u16x8*)(Wt + (size_t)(p * 64 + sa_m) * C_ + sa_g * 8);
            *(u16x8*)(&Bs_[p * 4096 + sa_off]) = v;
        }
    }
    __syncthreads();

    int cur = 0;
    for (int ks = 0; ks < 16; ks++) {
        const int k1 = (ks + 1) * 64;
        const bool more = (k1 < C_);
        float4 na0, na1;
        u16x8 nb0, nb1, nb2;
        if (more) {   // issue next tile's loads (overlap with compute)
            na0 = *(const float4*)(sa_src + k1);
            na1 = *(const float4*)(sa_src + k1 + 4);
            nb0 = *(const u16x8*)(Wt + (size_t)(0 * 64 + sa_m) * C_ + k1 + sa_g * 8);
            nb1 = *(const u16x8*)(Wt + (size_t)(1 * 64 + sa_m) * C_ + k1 + sa_g * 8);
            nb2 = *(const u16x8*)(Wt + (size_t)(2 * 64 + sa_m) * C_ + k1 + sa_g * 8);
        }
        // compute tile ks from buf^cur
        const unsigned short* Ac = As_ + cur * ABUF;
        const unsigned short* Bc = Bs_ + cur * BBUF;
        const int arow = ms * 16 + l16;
        bf16x8 a0 = load8_bf(&Ac[arow * 64 + ((quad ^ sw) * 8)]);
        bf16x8 a1 = load8_bf(&Ac[arow * 64 + (((quad + 4) ^ sw) * 8)]);
#pragma unroll
        for (int i = 0; i < 6; i++) {
            int brow = (nh * 6 + i) * 16 + l16;
            bf16x8 b0 = load8_bf(&Bc[brow * 64 + ((quad ^ sw) * 8)]);
            bf16x8 b1 = load8_bf(&Bc[brow * 64 + (((quad + 4) ^ sw) * 8)]);
            acc[i] = __builtin_amdgcn_mfma_f32_16x16x32_bf16(a0, b0, acc[i], 0, 0, 0);
            acc[i] = __builtin_amdgcn_mfma_f32_16x16x32_bf16(a1, b1, acc[i], 0, 0, 0);
        }
        if (more) {   // store next tile into buf^nxt, then single barrier
            const int nxt = cur ^ 1;
            *(u16x8*)(&As_[nxt * ABUF + sa_off]) = cvt8(na0, na1);
            *(u16x8*)(&Bs_[nxt * BBUF + 0 * 4096 + sa_off]) = nb0;
            *(u16x8*)(&Bs_[nxt * BBUF + 1 * 4096 + sa_off]) = nb1;
            *(u16x8*)(&Bs_[nxt * BBUF + 2 * 4096 + sa_off]) = nb2;
            __syncthreads();
            cur = nxt;
        }
    }

    // epilogue: C/D layout col=l16, row=quad*4+reg
    const int mrow_base = (int)r0 + ms * 16 + quad * 4;
#pragma unroll
    for (int i = 0; i < 6; i++) {
        int nt = nh * 6 + i;
#pragma unroll
        for (int r = 0; r < 4; r++) {
            int row = mrow_base + r;
            unsigned short bv = f2bf(acc[i][r]);
            if (nt < 4) {
                Qb[(size_t)row * H_ + nt * 16 + l16] = bv;
            } else if (nt < 8) {
                Kb[(size_t)row * H_ + (nt - 4) * 16 + l16] = bv;
            } else {
                int h = (nt - 8) * 16 + l16;
                int b = row >> 11;
                int t = row & (T_ - 1);
                VTb[((size_t)b * H_ + h) * T_ + t] = bv;
            }
        }
    }
}

// ---------------------------------------------------------------------------
// Kernel 2: flash attention, v5 (transposed-S formulation, KV-split x8).
// Grid = B * T/16 = 1024 blocks x 512 threads.  Block = 16 q-rows; wave s
// handles tiles t = s, s+8, ...  S^T = K*Q^T puts a single q per lane ->
// softmax state (m,l,alpha) is ONE scalar/lane; max/sum reductions are
// in-lane trees + 2 shuffles (was 8 shuffles).  PV computed as
// O^T = V^T * P^T: V^T A-frags load straight from global BEFORE softmax
// (latency overlapped); P^T goes through a wave-private LDS row-major
// [q][s] buffer (8 ds_write_b32 + 2 ds_read_b128).  8-way LSE merge in LDS,
// coalesced final store.
// ---------------------------------------------------------------------------
#define PROW 33   // u32 per P^T row (stride 33 -> spread banks)
#define OMS  65   // f32 per O-merge row

__global__ __launch_bounds__(512) void attn(
        const unsigned short* __restrict__ Qb,
        const unsigned short* __restrict__ Kb,
        const unsigned short* __restrict__ VTb,
        float* __restrict__ out) {
    __shared__ unsigned int ps_[8 * 16 * PROW];   // 16.5 KB
    __shared__ float Om_[8 * 16 * OMS];           // 33.3 KB
    __shared__ float mred_[8 * 16];
    __shared__ float lred_[8 * 16];

    const int tid  = threadIdx.x;
    const int wave = tid >> 6;            // KV-split index 0..7
    const int lane = tid & 63;
    const int l16  = lane & 15;
    const int quad = lane >> 4;
    const int b    = blockIdx.x >> 7;     // / (T/16)
    const int qt   = blockIdx.x & 127;
    const int q0   = qt * 16;
    const int tdiag = qt >> 2;            // diagonal 64-key tile index

    // Q as B-operand: B[n=q=l16][k=h=quad*8+j]
    const unsigned short* qrow =
        Qb + ((size_t)b * T_ + q0 + l16) * H_ + quad * 8;
    bf16x8 qf0 = load8_bf(qrow);
    bf16x8 qf1 = load8_bf(qrow + 32);

    f32x4 o[4];   // O^T C-frag: col=q=l16, row=h_local=quad*4+r (per ht)
#pragma unroll
    for (int i = 0; i < 4; i++) o[i] = (f32x4){0.f, 0.f, 0.f, 0.f};
    float m_run = -1e30f, l_run = 0.f;

    const float scale = 0.125f;  // 1/sqrt(H)
    const unsigned short* Kbase = Kb + (size_t)b * T_ * H_;
    const unsigned short* Vbase = VTb + (size_t)b * H_ * T_;
    unsigned int* Pw = &ps_[wave * 16 * PROW];

    for (int t = wave; t <= tdiag; t += 8) {
        // V^T A-frags: issue EARLY (independent of softmax)
        bf16x8 vf[8];
#pragma unroll
        for (int ht = 0; ht < 4; ht++)
#pragma unroll
            for (int ks = 0; ks < 2; ks++)
                vf[ht * 2 + ks] = load8_bf(
                    Vbase + (size_t)(ht * 16 + l16) * T_ + t * 64 + ks * 32 + quad * 8);

        // S^T = K * Q^T : A=K[s][h] (lane m=s_local=l16), B=Q
        f32x4 s[4];
#pragma unroll
        for (int nt = 0; nt < 4; nt++) {
            const unsigned short* krow =
                Kbase + (size_t)(t * 64 + nt * 16 + l16) * H_ + quad * 8;
            bf16x8 kf0 = load8_bf(krow);
            bf16x8 kf1 = load8_bf(krow + 32);
            f32x4 z = (f32x4){0.f, 0.f, 0.f, 0.f};
            z = __builtin_amdgcn_mfma_f32_16x16x32_bf16(kf0, qf0, z, 0, 0, 0);
            z = __builtin_amdgcn_mfma_f32_16x16x32_bf16(kf1, qf1, z, 0, 0, 0);
            s[nt] = z;   // S^T[s=t*64+nt*16+quad*4+r][q=l16]
        }

#pragma unroll
        for (int nt = 0; nt < 4; nt++)
#pragma unroll
            for (int r = 0; r < 4; r++) s[nt][r] *= scale;

        if (t == tdiag) {   // causal: mask s > q
#pragma unroll
            for (int nt = 0; nt < 4; nt++) {
#pragma unroll
                for (int r = 0; r < 4; r++) {
                    int key = t * 64 + nt * 16 + quad * 4 + r;
                    if (key > q0 + l16) s[nt][r] = -1e30f;
                }
            }
        }

        // softmax over s for this lane's q: in-lane tree + 2 cross-quad shuffles
        float mx;
        {
            float m0 = fmaxf(fmaxf(s[0][0], s[0][1]), fmaxf(s[0][2], s[0][3]));
            float m1 = fmaxf(fmaxf(s[1][0], s[1][1]), fmaxf(s[1][2], s[1][3]));
            float m2 = fmaxf(fmaxf(s[2][0], s[2][1]), fmaxf(s[2][2], s[2][3]));
            float m3 = fmaxf(fmaxf(s[3][0], s[3][1]), fmaxf(s[3][2], s[3][3]));
            mx = fmaxf(fmaxf(m0, m1), fmaxf(m2, m3));
        }
        mx = fmaxf(mx, __shfl_xor(mx, 16));
        mx = fmaxf(mx, __shfl_xor(mx, 32));
        const float m_new = fmaxf(m_run, mx);
        const float alpha = __expf(m_run - m_new);
        m_run = m_new;

        // P = exp(S^T - m_new): pack bf16 pairs, store P^T[q][s] rows to LDS
        float rs = 0.f;
#pragma unroll
        for (int nt = 0; nt < 4; nt++) {
#pragma unroll
            for (int i = 0; i < 2; i++) {
                float p0 = __expf(s[nt][2 * i]     - m_new);
                float p1 = __expf(s[nt][2 * i + 1] - m_new);
                rs += p0 + p1;
                Pw[l16 * PROW + nt * 8 + quad * 2 + i] = pack2(p0, p1);
            }
        }
        rs += __shfl_xor(rs, 16);
        rs += __shfl_xor(rs, 32);
        l_run = l_run * alpha + rs;

#pragma unroll
        for (int ht = 0; ht < 4; ht++)
#pragma unroll
            for (int r = 0; r < 4; r++) o[ht][r] *= alpha;

        // O^T += V^T * P^T : B-frag lane n=q=l16, k=s=ks*32+quad*8+j
#pragma unroll
        for (int ks = 0; ks < 2; ks++) {
            bf16x8 pB = __builtin_bit_cast(bf16x8,
                *(const u16x8*)(&Pw[l16 * PROW + ks * 16 + quad * 4]));
#pragma unroll
            for (int ht = 0; ht < 4; ht++)
                o[ht] = __builtin_amdgcn_mfma_f32_16x16x32_bf16(
                    vf[ht * 2 + ks], pB, o[ht], 0, 0, 0);
        }
    }

    // ---- 8-way LSE merge ----
#pragma unroll
    for (int ht = 0; ht < 4; ht++)
#pragma unroll
        for (int r = 0; r < 4; r++)
            Om_[(wave * 16 + l16) * OMS + ht * 16 + quad * 4 + r] = o[ht][r];
    if (quad == 0) {
        mred_[wave * 16 + l16] = m_run;
        lred_[wave * 16 + l16] = l_run;
    }
    __syncthreads();

    // finalize: thread -> (q, h); coalesced out write
    const int hcol = tid & 63;
    const int qrow0 = tid >> 6;   // 0..7
#pragma unroll
    for (int qq = 0; qq < 2; qq++) {
        const int q = qrow0 + qq * 8;
        float M = -1e30f;
#pragma unroll
        for (int w = 0; w < 8; w++) M = fmaxf(M, mred_[w * 16 + q]);
        float lt = 0.f, ov = 0.f;
#pragma unroll
        for (int w = 0; w < 8; w++) {
            float e = __expf(mred_[w * 16 + q] - M);
            lt += e * lred_[w * 16 + q];
            ov += e * Om_[(w * 16 + q) * OMS + hcol];
        }
        out[((size_t)b * T_ + q0 + q) * H_ + hcol] = ov / lt;
    }
}

// ---------------------------------------------------------------------------
extern "C" void kernel_launch(void* const* d_in, const int* in_sizes, int n_in,
                              void* d_out, int out_size, void* d_ws, size_t ws_size,
                              hipStream_t stream) {
    const float* x  = (const float*)d_in[0];
    const float* Wq = (const float*)d_in[1];
    const float* Wk = (const float*)d_in[2];
    const float* Wv = (const float*)d_in[3];
    float* out = (float*)d_out;

    unsigned short* Qb  = (unsigned short*)d_ws;
    unsigned short* Kb  = Qb  + (size_t)B_ * T_ * H_;
    unsigned short* VTb = Kb  + (size_t)B_ * T_ * H_;
    unsigned short* Wt  = VTb + (size_t)B_ * T_ * H_;

    cast_weights<<<(3 * C_ * H_) / 256, 256, 0, stream>>>(Wq, Wk, Wv, Wt);
    qkv_proj<<<(B_ * T_) / 64, 512, 0, stream>>>(x, Wt, Qb, Kb, VTb);
    attn<<<B_ * (T_ / 16), 512, 0, stream>>>(Qb, Kb, VTb, out);
}

// Round 6
// 147.885 us; speedup vs baseline: 1.6612x; 1.1070x over previous
//
#include <hip/hip_runtime.h>

// Problem constants (reference: B=8, T=2048, C=1024, H=64)
#define B_ 8
#define T_ 2048
#define C_ 1024
#define H_ 64

typedef __bf16 bf16x8 __attribute__((ext_vector_type(8)));
typedef float  f32x4  __attribute__((ext_vector_type(4)));
typedef unsigned short u16x8 __attribute__((ext_vector_type(8)));

// round-half-up f32 -> bf16 bits
__device__ __forceinline__ unsigned short f2bf(float f) {
    unsigned u = __builtin_bit_cast(unsigned, f);
    u += 0x8000u;
    return (unsigned short)(u >> 16);
}

__device__ __forceinline__ float bf2f(unsigned short v) {
    unsigned u = ((unsigned)v) << 16;
    return __builtin_bit_cast(float, u);
}

__device__ __forceinline__ unsigned pack2(float lo, float hi) {
    unsigned a = __builtin_bit_cast(unsigned, lo) + 0x8000u;
    unsigned b = __builtin_bit_cast(unsigned, hi) + 0x8000u;
    return (a >> 16) | (b & 0xffff0000u);
}

union U8 { unsigned u32[4]; u16x8 v; };

__device__ __forceinline__ u16x8 cvt8(float4 f0, float4 f1) {
    U8 r;
    r.u32[0] = pack2(f0.x, f0.y);
    r.u32[1] = pack2(f0.z, f0.w);
    r.u32[2] = pack2(f1.x, f1.y);
    r.u32[3] = pack2(f1.z, f1.w);
    return r.v;
}

__device__ __forceinline__ bf16x8 load8_bf(const unsigned short* p) {
    return __builtin_bit_cast(bf16x8, *(const u16x8*)p);
}

// Fragment-major layouts (written by qkv_proj, read by attn as contiguous
// 1KB-per-wave loads):
//   Qf/Kf[b][t16][part][l16*32 + quad*8 + j]   (t16 = seq/16, part = h/32)
//   Vf[b][s32][ht][l16*32 + quad*8 + j]        (s32 = seq/32, ht = h/16,
//                                               l16 = h%16, quad*8+j = seq%32)

// ---------------------------------------------------------------------------
// Kernel 0: pack Wq,Wk,Wv (fp32 [C][H]) into transposed bf16 Wt[192][C].
// ---------------------------------------------------------------------------
__global__ void cast_weights(const float* __restrict__ Wq,
                             const float* __restrict__ Wk,
                             const float* __restrict__ Wv,
                             unsigned short* __restrict__ Wt) {
    int idx = blockIdx.x * blockDim.x + threadIdx.x;
    int w   = idx >> 16;            // / (C*H) = 65536
    int rem = idx & 0xffff;
    int c   = rem & (C_ - 1);       // fastest -> coalesced Wt writes
    int h   = rem >> 10;
    const float* W = (w == 0) ? Wq : (w == 1) ? Wk : Wv;
    Wt[(size_t)(w * H_ + h) * C_ + c] = f2bf(W[(size_t)c * H_ + h]);
}

// ---------------------------------------------------------------------------
// Kernel 1: fused QKV projection, v6.
// Grid = (B*T/32) * 2 = 1024 blocks x 256 threads.  Block = 32 rows x 96 cols
// (nh = n-half of the 192 output cols); 4 waves: wave (ms = row-strip 0..1,
// nsub = n-sub 0..1) does 16 rows x 3 n-tiles.  Double-buffered LDS staging
// (32 KB total) -> 4 independent blocks/CU, 16 waves/CU: barrier stalls of
// one block are hidden by the other three (v5 had 1 block/CU).
// Epilogue writes fragment-major Qf/Kf/Vf (see layouts above).
// ---------------------------------------------------------------------------
#define ABUF 2048   // 32x64 bf16
#define BBUF 6144   // 96x64 bf16

__global__ __launch_bounds__(256) void qkv_proj(
        const float* __restrict__ x,
        const unsigned short* __restrict__ Wt,
        unsigned short* __restrict__ Qf,
        unsigned short* __restrict__ Kf,
        unsigned short* __restrict__ Vf) {
    __shared__ __attribute__((aligned(16))) unsigned short As_[2 * ABUF];  //  8 KB
    __shared__ __attribute__((aligned(16))) unsigned short Bs_[2 * BBUF];  // 24 KB

    const int tid  = threadIdx.x;
    const int wave = tid >> 6;
    const int lane = tid & 63;
    const int l16  = lane & 15;
    const int quad = lane >> 4;
    const int ms   = wave >> 1;          // row strip 0..1
    const int nsub = wave & 1;           // n-sub: 3 n-tiles each
    const int mb   = blockIdx.x >> 1;
    const int nh   = blockIdx.x & 1;     // n-half of 192 cols
    const size_t r0 = (size_t)mb * 32;

    // staging role: chunk c = p*256+tid -> row = p*32 + (tid>>3), group tid&7.
    const int srow = tid >> 3, sg = tid & 7;
    const float* sa_src = x + (r0 + srow) * C_ + sg * 8;
    const unsigned short* wb = Wt + (size_t)(nh * 96) * C_;
    const int a_off = srow * 64 + ((sg ^ (srow & 7)) * 8);  // XOR-swizzled; B: +p*2048

    f32x4 acc[3];
#pragma unroll
    for (int i = 0; i < 3; i++) acc[i] = (f32x4){0.f, 0.f, 0.f, 0.f};

    const int sw = l16 & 7;

    // prologue: stage k-step 0 into buf 0
    {
        float4 f0 = *(const float4*)(sa_src);
        float4 f1 = *(const float4*)(sa_src + 4);
        *(u16x8*)(&As_[a_off]) = cvt8(f0, f1);
#pragma unroll
        for (int p = 0; p < 3; p++) {
            u16x8 v = *(const u16x8*)(wb + (size_t)(p * 32 + srow) * C_ + sg * 8);
            *(u16x8*)(&Bs_[p * 2048 + a_off]) = v;
        }
    }
    __syncthreads();

    int cur = 0;
    for (int ks = 0; ks < 16; ks++) {
        const int k1 = (ks + 1) * 64;
        const bool more = (k1 < C_);
        float4 na0, na1;
        u16x8 nb0, nb1, nb2;
        if (more) {   // issue next tile's loads (overlap with compute)
            na0 = *(const float4*)(sa_src + k1);
            na1 = *(const float4*)(sa_src + k1 + 4);
            nb0 = *(const u16x8*)(wb + (size_t)(0 * 32 + srow) * C_ + k1 + sg * 8);
            nb1 = *(const u16x8*)(wb + (size_t)(1 * 32 + srow) * C_ + k1 + sg * 8);
            nb2 = *(const u16x8*)(wb + (size_t)(2 * 32 + srow) * C_ + k1 + sg * 8);
        }
        // compute tile ks from buf^cur
        const unsigned short* Ac = As_ + cur * ABUF;
        const unsigned short* Bc = Bs_ + cur * BBUF;
        const int arow = ms * 16 + l16;
        bf16x8 a0 = load8_bf(&Ac[arow * 64 + ((quad ^ sw) * 8)]);
        bf16x8 a1 = load8_bf(&Ac[arow * 64 + (((quad + 4) ^ sw) * 8)]);
#pragma unroll
        for (int i = 0; i < 3; i++) {
            int brow = (nsub * 3 + i) * 16 + l16;
            bf16x8 b0 = load8_bf(&Bc[brow * 64 + ((quad ^ sw) * 8)]);
            bf16x8 b1 = load8_bf(&Bc[brow * 64 + (((quad + 4) ^ sw) * 8)]);
            acc[i] = __builtin_amdgcn_mfma_f32_16x16x32_bf16(a0, b0, acc[i], 0, 0, 0);
            acc[i] = __builtin_amdgcn_mfma_f32_16x16x32_bf16(a1, b1, acc[i], 0, 0, 0);
        }
        if (more) {
            const int nxt = cur ^ 1;
            *(u16x8*)(&As_[nxt * ABUF + a_off]) = cvt8(na0, na1);
            *(u16x8*)(&Bs_[nxt * BBUF + 0 * 2048 + a_off]) = nb0;
            *(u16x8*)(&Bs_[nxt * BBUF + 1 * 2048 + a_off]) = nb1;
            *(u16x8*)(&Bs_[nxt * BBUF + 2 * 2048 + a_off]) = nb2;
            __syncthreads();
            cur = nxt;
        }
    }

    // epilogue: C/D layout col=l16, row=quad*4+reg -> fragment-major stores
#pragma unroll
    for (int i = 0; i < 3; i++) {
        int nt = nh * 6 + nsub * 3 + i;     // global n-tile 0..11
#pragma unroll
        for (int r = 0; r < 4; r++) {
            int row  = (int)r0 + ms * 16 + quad * 4 + r;
            int bb   = row >> 11;
            int tloc = row & (T_ - 1);
            unsigned short bv = f2bf(acc[i][r]);
            if (nt < 4) {            // Q: h = nt*16 + l16
                int part  = nt >> 1;
                int quadf = (nt & 1) * 2 + (l16 >> 3);
                Qf[((size_t)(bb * 128 + (tloc >> 4)) * 2 + part) * 512
                   + (tloc & 15) * 32 + quadf * 8 + (l16 & 7)] = bv;
            } else if (nt < 8) {     // K: h = (nt-4)*16 + l16
                int nk    = nt - 4;
                int part  = nk >> 1;
                int quadf = (nk & 1) * 2 + (l16 >> 3);
                Kf[((size_t)(bb * 128 + (tloc >> 4)) * 2 + part) * 512
                   + (tloc & 15) * 32 + quadf * 8 + (l16 & 7)] = bv;
            } else {                 // V: ht = nt-8, h%16 = l16, seq = row
                int ht  = nt - 8;
                int s32 = tloc >> 5;
                int w32 = tloc & 31;
                Vf[((size_t)(bb * 64 + s32) * 4 + ht) * 512
                   + l16 * 32 + (w32 >> 3) * 8 + (w32 & 7)] = bv;
            }
        }
    }
}

// ---------------------------------------------------------------------------
// Kernel 2: flash attention, v6 (fragment-major loads, bf16 merge buffer).
// Structure as v5 (transposed-S, KV-split x8, 1024 blocks x 512 thr), but
// every Q/K/V fragment load is now a contiguous 1KB-per-wave load (was a
// 16-segment gather), and the O-merge buffer is bf16 -> LDS 34.8 KB ->
// 4 blocks/CU (was 3).
// ---------------------------------------------------------------------------
#define PROW 33   // u32 per P^T row
#define OMS2 66   // u16 per O-merge row

__global__ __launch_bounds__(512) void attn(
        const unsigned short* __restrict__ Qf,
        const unsigned short* __restrict__ Kf,
        const unsigned short* __restrict__ Vf,
        float* __restrict__ out) {
    __shared__ unsigned int ps_[8 * 16 * PROW];     // 16.9 KB
    __shared__ unsigned short Om_[8 * 16 * OMS2];   // 16.9 KB
    __shared__ float mred_[8 * 16];
    __shared__ float lred_[8 * 16];

    const int tid  = threadIdx.x;
    const int wave = tid >> 6;            // KV-split index 0..7
    const int lane = tid & 63;
    const int l16  = lane & 15;
    const int quad = lane >> 4;
    const int b    = blockIdx.x >> 7;     // / (T/16)
    const int qt   = blockIdx.x & 127;
    const int q0   = qt * 16;
    const int tdiag = qt >> 2;            // diagonal 64-key tile index

    const int loff = l16 * 32 + quad * 8; // fragment lane offset (u16)

    // Q as B-operand: B[n=q=l16][k=h]
    const unsigned short* Qfb = Qf + (size_t)(b * 128 + qt) * 1024;
    bf16x8 qf0 = load8_bf(Qfb + loff);
    bf16x8 qf1 = load8_bf(Qfb + 512 + loff);

    f32x4 o[4];   // O^T C-frag: col=q=l16, row=h_local
#pragma unroll
    for (int i = 0; i < 4; i++) o[i] = (f32x4){0.f, 0.f, 0.f, 0.f};
    float m_run = -1e30f, l_run = 0.f;

    const float scale = 0.125f;  // 1/sqrt(H)
    const unsigned short* Kfb = Kf + (size_t)b * 128 * 1024;
    const unsigned short* Vfb = Vf + (size_t)b * 64 * 2048;
    unsigned int* Pw = &ps_[wave * 16 * PROW];

    for (int t = wave; t <= tdiag; t += 8) {
        // V^T A-frags: contiguous 1KB loads, issued EARLY
        bf16x8 vf[8];
#pragma unroll
        for (int ks = 0; ks < 2; ks++)
#pragma unroll
            for (int ht = 0; ht < 4; ht++)
                vf[ht * 2 + ks] = load8_bf(
                    Vfb + ((size_t)(t * 2 + ks) * 4 + ht) * 512 + loff);

        // S^T = K * Q^T : A=K fragment (contiguous 1KB loads)
        f32x4 s[4];
#pragma unroll
        for (int nt = 0; nt < 4; nt++) {
            const unsigned short* kp = Kfb + (size_t)(t * 4 + nt) * 1024;
            bf16x8 kf0 = load8_bf(kp + loff);
            bf16x8 kf1 = load8_bf(kp + 512 + loff);
            f32x4 z = (f32x4){0.f, 0.f, 0.f, 0.f};
            z = __builtin_amdgcn_mfma_f32_16x16x32_bf16(kf0, qf0, z, 0, 0, 0);
            z = __builtin_amdgcn_mfma_f32_16x16x32_bf16(kf1, qf1, z, 0, 0, 0);
            s[nt] = z;   // S^T[s = t*64+nt*16+quad*4+r][q = l16]
        }

#pragma unroll
        for (int nt = 0; nt < 4; nt++)
#pragma unroll
            for (int r = 0; r < 4; r++) s[nt][r] *= scale;

        if (t == tdiag) {   // causal: mask s > q
#pragma unroll
            for (int nt = 0; nt < 4; nt++) {
#pragma unroll
                for (int r = 0; r < 4; r++) {
                    int key = t * 64 + nt * 16 + quad * 4 + r;
                    if (key > q0 + l16) s[nt][r] = -1e30f;
                }
            }
        }

        // softmax over s for this lane's q: in-lane tree + 2 cross-quad shuffles
        float mx;
        {
            float m0 = fmaxf(fmaxf(s[0][0], s[0][1]), fmaxf(s[0][2], s[0][3]));
            float m1 = fmaxf(fmaxf(s[1][0], s[1][1]), fmaxf(s[1][2], s[1][3]));
            float m2 = fmaxf(fmaxf(s[2][0], s[2][1]), fmaxf(s[2][2], s[2][3]));
            float m3 = fmaxf(fmaxf(s[3][0], s[3][1]), fmaxf(s[3][2], s[3][3]));
            mx = fmaxf(fmaxf(m0, m1), fmaxf(m2, m3));
        }
        mx = fmaxf(mx, __shfl_xor(mx, 16));
        mx = fmaxf(mx, __shfl_xor(mx, 32));
        const float m_new = fmaxf(m_run, mx);
        const float alpha = __expf(m_run - m_new);
        m_run = m_new;

        // P = exp(S^T - m_new): pack bf16 pairs, store P^T[q][s] rows to LDS
        float rs = 0.f;
#pragma unroll
        for (int nt = 0; nt < 4; nt++) {
#pragma unroll
            for (int i = 0; i < 2; i++) {
                float p0 = __expf(s[nt][2 * i]     - m_new);
                float p1 = __expf(s[nt][2 * i + 1] - m_new);
                rs += p0 + p1;
                Pw[l16 * PROW + nt * 8 + quad * 2 + i] = pack2(p0, p1);
            }
        }
        rs += __shfl_xor(rs, 16);
        rs += __shfl_xor(rs, 32);
        l_run = l_run * alpha + rs;

#pragma unroll
        for (int ht = 0; ht < 4; ht++)
#pragma unroll
            for (int r = 0; r < 4; r++) o[ht][r] *= alpha;

        // O^T += V^T * P^T : B-frag lane n=q=l16, k=s
#pragma unroll
        for (int ks = 0; ks < 2; ks++) {
            bf16x8 pB = __builtin_bit_cast(bf16x8,
                *(const u16x8*)(&Pw[l16 * PROW + ks * 16 + quad * 4]));
#pragma unroll
            for (int ht = 0; ht < 4; ht++)
                o[ht] = __builtin_amdgcn_mfma_f32_16x16x32_bf16(
                    vf[ht * 2 + ks], pB, o[ht], 0, 0, 0);
        }
    }

    // ---- 8-way LSE merge (O partials in bf16: rel err 2^-9, bounded
    //      relative to |v| since o_w scales with l_w -> ~0.006 abs) ----
#pragma unroll
    for (int ht = 0; ht < 4; ht++)
#pragma unroll
        for (int r = 0; r < 4; r++)
            Om_[(wave * 16 + l16) * OMS2 + ht * 16 + quad * 4 + r] = f2bf(o[ht][r]);
    if (quad == 0) {
        mred_[wave * 16 + l16] = m_run;
        lred_[wave * 16 + l16] = l_run;
    }
    __syncthreads();

    // finalize: thread -> (q, h); coalesced out write
    const int hcol = tid & 63;
    const int qrow0 = tid >> 6;   // 0..7
#pragma unroll
    for (int qq = 0; qq < 2; qq++) {
        const int q = qrow0 + qq * 8;
        float M = -1e30f;
#pragma unroll
        for (int w = 0; w < 8; w++) M = fmaxf(M, mred_[w * 16 + q]);
        float lt = 0.f, ov = 0.f;
#pragma unroll
        for (int w = 0; w < 8; w++) {
            float e = __expf(mred_[w * 16 + q] - M);
            lt += e * lred_[w * 16 + q];
            ov += e * bf2f(Om_[(w * 16 + q) * OMS2 + hcol]);
        }
        out[((size_t)b * T_ + q0 + q) * H_ + hcol] = ov / lt;
    }
}

// ---------------------------------------------------------------------------
extern "C" void kernel_launch(void* const* d_in, const int* in_sizes, int n_in,
                              void* d_out, int out_size, void* d_ws, size_t ws_size,
                              hipStream_t stream) {
    const float* x  = (const float*)d_in[0];
    const float* Wq = (const float*)d_in[1];
    const float* Wk = (const float*)d_in[2];
    const float* Wv = (const float*)d_in[3];
    float* out = (float*)d_out;

    unsigned short* Qf = (unsigned short*)d_ws;                 // 1M elems
    unsigned short* Kf = Qf + (size_t)B_ * T_ * H_;             // 1M elems
    unsigned short* Vf = Kf + (size_t)B_ * T_ * H_;             // 1M elems
    unsigned short* Wt = Vf + (size_t)B_ * T_ * H_;             // 192K elems

    cast_weights<<<(3 * C_ * H_) / 256, 256, 0, stream>>>(Wq, Wk, Wv, Wt);
    qkv_proj<<<(B_ * T_ / 32) * 2, 256, 0, stream>>>(x, Wt, Qf, Kf, Vf);
    attn<<<B_ * (T_ / 16), 512, 0, stream>>>(Qf, Kf, Vf, out);
}

// Round 7
// 141.864 us; speedup vs baseline: 1.7317x; 1.0424x over previous
//
#include <hip/hip_runtime.h>

// Problem constants (reference: B=8, T=2048, C=1024, H=64)
#define B_ 8
#define T_ 2048
#define C_ 1024
#define H_ 64

typedef __bf16 bf16x8 __attribute__((ext_vector_type(8)));
typedef float  f32x4  __attribute__((ext_vector_type(4)));
typedef unsigned short u16x8 __attribute__((ext_vector_type(8)));

// round-half-up f32 -> bf16 bits
__device__ __forceinline__ unsigned short f2bf(float f) {
    unsigned u = __builtin_bit_cast(unsigned, f);
    u += 0x8000u;
    return (unsigned short)(u >> 16);
}

__device__ __forceinline__ float bf2f(unsigned short v) {
    unsigned u = ((unsigned)v) << 16;
    return __builtin_bit_cast(float, u);
}

__device__ __forceinline__ unsigned pack2(float lo, float hi) {
    unsigned a = __builtin_bit_cast(unsigned, lo) + 0x8000u;
    unsigned b = __builtin_bit_cast(unsigned, hi) + 0x8000u;
    return (a >> 16) | (b & 0xffff0000u);
}

union U8 { unsigned u32[4]; u16x8 v; };

__device__ __forceinline__ u16x8 cvt8(float4 f0, float4 f1) {
    U8 r;
    r.u32[0] = pack2(f0.x, f0.y);
    r.u32[1] = pack2(f0.z, f0.w);
    r.u32[2] = pack2(f1.x, f1.y);
    r.u32[3] = pack2(f1.z, f1.w);
    return r.v;
}

__device__ __forceinline__ bf16x8 load8_bf(const unsigned short* p) {
    return __builtin_bit_cast(bf16x8, *(const u16x8*)p);
}

// Fragment-major layouts (contiguous 1KB-per-wave loads):
//   Qf/Kf[b][t16][part][l16*32 + quad*8 + j]   (t16 = seq/16, part = h/32)
//   Vf[b][s32][ht][l16*32 + quad*8 + j]        (s32 = seq/32, ht = h/16)
//   Wtf[nt][kc][l16*32 + quad*8 + j]           (nt = ncol/16 of 192, kc = c/32)

// ---------------------------------------------------------------------------
// Kernel 0: pack Wq,Wk,Wv (fp32 [C][H]) straight into fragment-major Wtf.
// ---------------------------------------------------------------------------
__global__ void cast_weights(const float* __restrict__ Wq,
                             const float* __restrict__ Wk,
                             const float* __restrict__ Wv,
                             unsigned short* __restrict__ Wtf) {
    int idx = blockIdx.x * blockDim.x + threadIdx.x;   // 0 .. 192*1024-1
    int n   = idx % 192;        // global out col (reads coalesced over n)
    int c   = idx / 192;        // k index
    int w   = n >> 6;
    int h   = n & 63;
    const float* W = (w == 0) ? Wq : (w == 1) ? Wk : Wv;
    int nt = n >> 4, l16 = n & 15;
    int kc = c >> 5, quad = (c >> 3) & 3, j = c & 7;
    Wtf[(size_t)(nt * 32 + kc) * 512 + l16 * 32 + quad * 8 + j] =
        f2bf(W[(size_t)c * H_ + h]);
}

// ---------------------------------------------------------------------------
// Kernel 1: fused QKV projection, v7 (barrier-free K-loop).
// Grid = B*T/32 = 512 blocks x 512 threads (8 waves; 64KB LDS -> 2 blocks/CU,
// 16 waves/CU).  Stage the block's WHOLE 32-row x-strip into LDS once
// (coalesced fp32 reads, bf16 convert, XOR-swizzled), one barrier, then a
// 32-step K-loop with NO barriers: A = ds_read_b128 from static LDS,
// B = contiguous 1KB fragment loads from Wtf (XCD-L2-resident, replicated),
// 3 MFMAs.  Compiler pipelines the B loads freely (no barrier fences).
// Wave (ms = w>>2, ns = w&3): rows ms*16..+15, n-tiles 3ns..3ns+2.
// ---------------------------------------------------------------------------
__global__ __launch_bounds__(512) void qkv_proj(
        const float* __restrict__ x,
        const unsigned short* __restrict__ Wtf,
        unsigned short* __restrict__ Qf,
        unsigned short* __restrict__ Kf,
        unsigned short* __restrict__ Vf) {
    __shared__ __attribute__((aligned(16))) unsigned short As_[32 * 1024]; // 64 KB

    const int tid  = threadIdx.x;
    const int wave = tid >> 6;
    const int lane = tid & 63;
    const int l16  = lane & 15;
    const int quad = lane >> 4;
    const int ms   = wave >> 2;          // row strip 0..1
    const int ns   = wave & 3;           // n-quarter: 3 n-tiles each
    const size_t r0 = (size_t)blockIdx.x * 32;

    // ---- stage x[r0..r0+32)[0..1024) -> As_ (bf16, XOR-swizzled 16B groups)
#pragma unroll
    for (int i = 0; i < 8; i++) {
        int c   = i * 512 + tid;         // chunk 0..4095
        int row = c >> 7;                // 0..31
        int g   = c & 127;               // 16B group within row
        const float* p = x + (r0 + row) * C_ + g * 8;
        float4 f0 = *(const float4*)p;
        float4 f1 = *(const float4*)(p + 4);
        int off = row * 1024 + ((g & ~7) + ((g & 7) ^ (row & 7))) * 8;
        *(u16x8*)(&As_[off]) = cvt8(f0, f1);
    }
    __syncthreads();

    f32x4 acc[3];
#pragma unroll
    for (int i = 0; i < 3; i++) acc[i] = (f32x4){0.f, 0.f, 0.f, 0.f};

    const int arow = ms * 16 + l16;
    const int sw   = l16 & 7;
    const int loff = l16 * 32 + quad * 8;   // fragment lane offset
    const unsigned short* wb = Wtf + (size_t)(ns * 3) * 32 * 512;

#pragma unroll 4
    for (int kc = 0; kc < 32; kc++) {
        int g = kc * 4 + quad;
        bf16x8 a = load8_bf(&As_[arow * 1024 + ((g & ~7) + ((g & 7) ^ sw)) * 8]);
#pragma unroll
        for (int i = 0; i < 3; i++) {
            bf16x8 b = load8_bf(wb + (size_t)(i * 32 + kc) * 512 + loff);
            acc[i] = __builtin_amdgcn_mfma_f32_16x16x32_bf16(a, b, acc[i], 0, 0, 0);
        }
    }

    // epilogue: C/D layout col=l16, row=quad*4+reg -> fragment-major stores
#pragma unroll
    for (int i = 0; i < 3; i++) {
        int nt = ns * 3 + i;                 // global n-tile 0..11
#pragma unroll
        for (int r = 0; r < 4; r++) {
            int row  = (int)r0 + ms * 16 + quad * 4 + r;
            int bb   = row >> 11;
            int tloc = row & (T_ - 1);
            unsigned short bv = f2bf(acc[i][r]);
            if (nt < 4) {            // Q: h = nt*16 + l16
                int part  = nt >> 1;
                int quadf = (nt & 1) * 2 + (l16 >> 3);
                Qf[((size_t)(bb * 128 + (tloc >> 4)) * 2 + part) * 512
                   + (tloc & 15) * 32 + quadf * 8 + (l16 & 7)] = bv;
            } else if (nt < 8) {     // K
                int nk    = nt - 4;
                int part  = nk >> 1;
                int quadf = (nk & 1) * 2 + (l16 >> 3);
                Kf[((size_t)(bb * 128 + (tloc >> 4)) * 2 + part) * 512
                   + (tloc & 15) * 32 + quadf * 8 + (l16 & 7)] = bv;
            } else {                 // V
                int ht  = nt - 8;
                int s32 = tloc >> 5;
                int w32 = tloc & 31;
                Vf[((size_t)(bb * 64 + s32) * 4 + ht) * 512
                   + l16 * 32 + (w32 >> 3) * 8 + (w32 & 7)] = bv;
            }
        }
    }
}

// ---------------------------------------------------------------------------
// Kernel 2: flash attention, v7 = v6 + XCD batch-affinity swizzle.
// b = blockIdx & 7: round-robin block->XCD dispatch puts all blocks of one
// batch on one XCD, so that batch's KV (768 KB) is L2-resident -> the 64x
// tile re-read amplification (270 MB device-wide) flows at per-XCD L2 BW
// instead of Infinity-Cache BW.
// ---------------------------------------------------------------------------
#define PROW 33   // u32 per P^T row
#define OMS2 66   // u16 per O-merge row

__global__ __launch_bounds__(512) void attn(
        const unsigned short* __restrict__ Qf,
        const unsigned short* __restrict__ Kf,
        const unsigned short* __restrict__ Vf,
        float* __restrict__ out) {
    __shared__ unsigned int ps_[8 * 16 * PROW];     // 16.9 KB
    __shared__ unsigned short Om_[8 * 16 * OMS2];   // 16.9 KB
    __shared__ float mred_[8 * 16];
    __shared__ float lred_[8 * 16];

    const int tid  = threadIdx.x;
    const int wave = tid >> 6;            // KV-split index 0..7
    const int lane = tid & 63;
    const int l16  = lane & 15;
    const int quad = lane >> 4;
    const int b    = blockIdx.x & 7;      // XCD-affinity: batch = XCD
    const int qt   = blockIdx.x >> 3;     // 0..127
    const int q0   = qt * 16;
    const int tdiag = qt >> 2;            // diagonal 64-key tile index

    const int loff = l16 * 32 + quad * 8; // fragment lane offset (u16)

    // Q as B-operand: B[n=q=l16][k=h]
    const unsigned short* Qfb = Qf + (size_t)(b * 128 + qt) * 1024;
    bf16x8 qf0 = load8_bf(Qfb + loff);
    bf16x8 qf1 = load8_bf(Qfb + 512 + loff);

    f32x4 o[4];   // O^T C-frag: col=q=l16, row=h_local
#pragma unroll
    for (int i = 0; i < 4; i++) o[i] = (f32x4){0.f, 0.f, 0.f, 0.f};
    float m_run = -1e30f, l_run = 0.f;

    const float scale = 0.125f;  // 1/sqrt(H)
    const unsigned short* Kfb = Kf + (size_t)b * 128 * 1024;
    const unsigned short* Vfb = Vf + (size_t)b * 64 * 2048;
    unsigned int* Pw = &ps_[wave * 16 * PROW];

    for (int t = wave; t <= tdiag; t += 8) {
        // V^T A-frags: contiguous 1KB loads, issued EARLY
        bf16x8 vf[8];
#pragma unroll
        for (int ks = 0; ks < 2; ks++)
#pragma unroll
            for (int ht = 0; ht < 4; ht++)
                vf[ht * 2 + ks] = load8_bf(
                    Vfb + ((size_t)(t * 2 + ks) * 4 + ht) * 512 + loff);

        // S^T = K * Q^T : A=K fragment (contiguous 1KB loads)
        f32x4 s[4];
#pragma unroll
        for (int nt = 0; nt < 4; nt++) {
            const unsigned short* kp = Kfb + (size_t)(t * 4 + nt) * 1024;
            bf16x8 kf0 = load8_bf(kp + loff);
            bf16x8 kf1 = load8_bf(kp + 512 + loff);
            f32x4 z = (f32x4){0.f, 0.f, 0.f, 0.f};
            z = __builtin_amdgcn_mfma_f32_16x16x32_bf16(kf0, qf0, z, 0, 0, 0);
            z = __builtin_amdgcn_mfma_f32_16x16x32_bf16(kf1, qf1, z, 0, 0, 0);
            s[nt] = z;   // S^T[s = t*64+nt*16+quad*4+r][q = l16]
        }

#pragma unroll
        for (int nt = 0; nt < 4; nt++)
#pragma unroll
            for (int r = 0; r < 4; r++) s[nt][r] *= scale;

        if (t == tdiag) {   // causal: mask s > q
#pragma unroll
            for (int nt = 0; nt < 4; nt++) {
#pragma unroll
                for (int r = 0; r < 4; r++) {
                    int key = t * 64 + nt * 16 + quad * 4 + r;
                    if (key > q0 + l16) s[nt][r] = -1e30f;
                }
            }
        }

        // softmax over s for this lane's q: in-lane tree + 2 cross-quad shuffles
        float mx;
        {
            float m0 = fmaxf(fmaxf(s[0][0], s[0][1]), fmaxf(s[0][2], s[0][3]));
            float m1 = fmaxf(fmaxf(s[1][0], s[1][1]), fmaxf(s[1][2], s[1][3]));
            float m2 = fmaxf(fmaxf(s[2][0], s[2][1]), fmaxf(s[2][2], s[2][3]));
            float m3 = fmaxf(fmaxf(s[3][0], s[3][1]), fmaxf(s[3][2], s[3][3]));
            mx = fmaxf(fmaxf(m0, m1), fmaxf(m2, m3));
        }
        mx = fmaxf(mx, __shfl_xor(mx, 16));
        mx = fmaxf(mx, __shfl_xor(mx, 32));
        const float m_new = fmaxf(m_run, mx);
        const float alpha = __expf(m_run - m_new);
        m_run = m_new;

        // P = exp(S^T - m_new): pack bf16 pairs, store P^T[q][s] rows to LDS
        float rs = 0.f;
#pragma unroll
        for (int nt = 0; nt < 4; nt++) {
#pragma unroll
            for (int i = 0; i < 2; i++) {
                float p0 = __expf(s[nt][2 * i]     - m_new);
                float p1 = __expf(s[nt][2 * i + 1] - m_new);
                rs += p0 + p1;
                Pw[l16 * PROW + nt * 8 + quad * 2 + i] = pack2(p0, p1);
            }
        }
        rs += __shfl_xor(rs, 16);
        rs += __shfl_xor(rs, 32);
        l_run = l_run * alpha + rs;

#pragma unroll
        for (int ht = 0; ht < 4; ht++)
#pragma unroll
            for (int r = 0; r < 4; r++) o[ht][r] *= alpha;

        // O^T += V^T * P^T : B-frag lane n=q=l16, k=s
#pragma unroll
        for (int ks = 0; ks < 2; ks++) {
            bf16x8 pB = __builtin_bit_cast(bf16x8,
                *(const u16x8*)(&Pw[l16 * PROW + ks * 16 + quad * 4]));
#pragma unroll
            for (int ht = 0; ht < 4; ht++)
                o[ht] = __builtin_amdgcn_mfma_f32_16x16x32_bf16(
                    vf[ht * 2 + ks], pB, o[ht], 0, 0, 0);
        }
    }

    // ---- 8-way LSE merge (O partials in bf16) ----
#pragma unroll
    for (int ht = 0; ht < 4; ht++)
#pragma unroll
        for (int r = 0; r < 4; r++)
            Om_[(wave * 16 + l16) * OMS2 + ht * 16 + quad * 4 + r] = f2bf(o[ht][r]);
    if (quad == 0) {
        mred_[wave * 16 + l16] = m_run;
        lred_[wave * 16 + l16] = l_run;
    }
    __syncthreads();

    // finalize: thread -> (q, h); coalesced out write
    const int hcol = tid & 63;
    const int qrow0 = tid >> 6;   // 0..7
#pragma unroll
    for (int qq = 0; qq < 2; qq++) {
        const int q = qrow0 + qq * 8;
        float M = -1e30f;
#pragma unroll
        for (int w = 0; w < 8; w++) M = fmaxf(M, mred_[w * 16 + q]);
        float lt = 0.f, ov = 0.f;
#pragma unroll
        for (int w = 0; w < 8; w++) {
            float e = __expf(mred_[w * 16 + q] - M);
            lt += e * lred_[w * 16 + q];
            ov += e * bf2f(Om_[(w * 16 + q) * OMS2 + hcol]);
        }
        out[((size_t)b * T_ + q0 + q) * H_ + hcol] = ov / lt;
    }
}

// ---------------------------------------------------------------------------
extern "C" void kernel_launch(void* const* d_in, const int* in_sizes, int n_in,
                              void* d_out, int out_size, void* d_ws, size_t ws_size,
                              hipStream_t stream) {
    const float* x  = (const float*)d_in[0];
    const float* Wq = (const float*)d_in[1];
    const float* Wk = (const float*)d_in[2];
    const float* Wv = (const float*)d_in[3];
    float* out = (float*)d_out;

    unsigned short* Qf  = (unsigned short*)d_ws;
    unsigned short* Kf  = Qf + (size_t)B_ * T_ * H_;
    unsigned short* Vf  = Kf + (size_t)B_ * T_ * H_;
    unsigned short* Wtf = Vf + (size_t)B_ * T_ * H_;

    cast_weights<<<(192 * C_) / 256, 256, 0, stream>>>(Wq, Wk, Wv, Wtf);
    qkv_proj<<<B_ * T_ / 32, 512, 0, stream>>>(x, Wtf, Qf, Kf, Vf);
    attn<<<B_ * (T_ / 16), 512, 0, stream>>>(Qf, Kf, Vf, out);
}

// Round 8
// 141.407 us; speedup vs baseline: 1.7373x; 1.0032x over previous
//
#include <hip/hip_runtime.h>

// Problem constants (reference: B=8, T=2048, C=1024, H=64)
#define B_ 8
#define T_ 2048
#define C_ 1024
#define H_ 64

typedef __bf16 bf16x8 __attribute__((ext_vector_type(8)));
typedef float  f32x4  __attribute__((ext_vector_type(4)));
typedef unsigned short u16x8 __attribute__((ext_vector_type(8)));

// round-half-up f32 -> bf16 bits
__device__ __forceinline__ unsigned short f2bf(float f) {
    unsigned u = __builtin_bit_cast(unsigned, f);
    u += 0x8000u;
    return (unsigned short)(u >> 16);
}

__device__ __forceinline__ float bf2f(unsigned short v) {
    unsigned u = ((unsigned)v) << 16;
    return __builtin_bit_cast(float, u);
}

__device__ __forceinline__ unsigned pack2(float lo, float hi) {
    unsigned a = __builtin_bit_cast(unsigned, lo) + 0x8000u;
    unsigned b = __builtin_bit_cast(unsigned, hi) + 0x8000u;
    return (a >> 16) | (b & 0xffff0000u);
}

union U8 { unsigned u32[4]; u16x8 v; };

__device__ __forceinline__ u16x8 cvt8(float4 f0, float4 f1) {
    U8 r;
    r.u32[0] = pack2(f0.x, f0.y);
    r.u32[1] = pack2(f0.z, f0.w);
    r.u32[2] = pack2(f1.x, f1.y);
    r.u32[3] = pack2(f1.z, f1.w);
    return r.v;
}

__device__ __forceinline__ bf16x8 load8_bf(const unsigned short* p) {
    return __builtin_bit_cast(bf16x8, *(const u16x8*)p);
}

// Fragment-major layouts (contiguous 1KB-per-wave loads):
//   Qf/Kf[b][t16][part][l16*32 + quad*8 + j]   (t16 = seq/16, part = h/32)
//   Vf[b][s32][ht][l16*32 + quad*8 + j]        (s32 = seq/32, ht = h/16)
//   Wtf[nt][kk][l16*32 + quad*8 + j]           (nt = ncol/16 of 192, kk = c/32)

// ---------------------------------------------------------------------------
// Kernel 0: pack Wq,Wk,Wv (fp32 [C][H]) straight into fragment-major Wtf.
// ---------------------------------------------------------------------------
__global__ void cast_weights(const float* __restrict__ Wq,
                             const float* __restrict__ Wk,
                             const float* __restrict__ Wv,
                             unsigned short* __restrict__ Wtf) {
    int idx = blockIdx.x * blockDim.x + threadIdx.x;   // 0 .. 192*1024-1
    int n   = idx % 192;        // global out col
    int c   = idx / 192;        // k index
    int w   = n >> 6;
    int h   = n & 63;
    const float* W = (w == 0) ? Wq : (w == 1) ? Wk : Wv;
    int nt = n >> 4, l16 = n & 15;
    int kk = c >> 5, quad = (c >> 3) & 3, j = c & 7;
    Wtf[(size_t)(nt * 32 + kk) * 512 + l16 * 32 + quad * 8 + j] =
        f2bf(W[(size_t)c * H_ + h]);
}

// ---------------------------------------------------------------------------
// Kernel 1: fused QKV projection, v8.
// Grid = B*T/32 = 512 blocks x 256 threads (4 waves).  Block = 32 rows x 192.
// x staged in two 512-k halves (32 KB LDS, reused) -> 5 blocks/CU, 20 w/CU.
// Wave ns owns n-tiles 3ns..3ns+2 and BOTH 16-row m-strips: per k-step
// 2 ds_read_b128 (A) + 3 contiguous 1KB B-loads (Wtf, L2) + 6 MFMA — each
// B fragment feeds 2 MFMAs in-register (v7 read it twice through L1).
// Epilogue: accs -> LDS fragment-major assembly buffer (reuses As_), then
// 12 x 1KB coalesced chunk copies (v7 did 12 scattered u16 stores/thread).
// ---------------------------------------------------------------------------
__global__ __launch_bounds__(256) void qkv_proj(
        const float* __restrict__ x,
        const unsigned short* __restrict__ Wtf,
        unsigned short* __restrict__ Qf,
        unsigned short* __restrict__ Kf,
        unsigned short* __restrict__ Vf) {
    __shared__ __attribute__((aligned(16))) unsigned short As_[32 * 512]; // 32 KB

    const int tid  = threadIdx.x;
    const int ns   = tid >> 6;           // wave = n-quarter (3 n-tiles)
    const int lane = tid & 63;
    const int l16  = lane & 15;
    const int quad = lane >> 4;
    const size_t r0 = (size_t)blockIdx.x * 32;
    const int bb    = (int)(r0 >> 11);
    const int tloc0 = (int)(r0 & (T_ - 1));
    const int t16_0 = tloc0 >> 4;
    const int s32   = tloc0 >> 5;

    f32x4 acc[6];   // [ms*3 + i]
#pragma unroll
    for (int i = 0; i < 6; i++) acc[i] = (f32x4){0.f, 0.f, 0.f, 0.f};

    const int sw   = l16 & 7;
    const int loff = l16 * 32 + quad * 8;

    for (int p = 0; p < 2; p++) {
        if (p) __syncthreads();          // phase-0 reads done before overwrite
        // ---- stage x[r0..r0+32)[p*512..+512) -> As_ (bf16, XOR-swizzled) ----
#pragma unroll
        for (int i = 0; i < 8; i++) {
            int c   = i * 256 + tid;     // granule 0..2047
            int row = c >> 6;            // 0..31
            int g   = c & 63;            // 16B group within 512-k row
            const float* sp = x + (r0 + row) * C_ + p * 512 + g * 8;
            float4 f0 = *(const float4*)sp;
            float4 f1 = *(const float4*)(sp + 4);
            int off = row * 512 + ((g & ~7) + ((g & 7) ^ (row & 7))) * 8;
            *(u16x8*)(&As_[off]) = cvt8(f0, f1);
        }
        __syncthreads();

#pragma unroll 4
        for (int kc = 0; kc < 16; kc++) {
            int g  = kc * 4 + quad;
            int gs = ((g & ~7) + ((g & 7) ^ sw)) * 8;
            bf16x8 a0 = load8_bf(&As_[l16 * 512 + gs]);
            bf16x8 a1 = load8_bf(&As_[(16 + l16) * 512 + gs]);
            int kk = p * 16 + kc;
#pragma unroll
            for (int i = 0; i < 3; i++) {
                bf16x8 b = load8_bf(Wtf + (size_t)((ns * 3 + i) * 32 + kk) * 512 + loff);
                acc[i]     = __builtin_amdgcn_mfma_f32_16x16x32_bf16(a0, b, acc[i],     0, 0, 0);
                acc[3 + i] = __builtin_amdgcn_mfma_f32_16x16x32_bf16(a1, b, acc[3 + i], 0, 0, 0);
            }
        }
    }

    // ---- epilogue: assemble fragment-major chunks in LDS, then coalesced copy
    __syncthreads();                     // all ds_reads done; reuse As_ as E
    unsigned short* E = As_;             // 12 chunks x 512 u16 = 12 KB
#pragma unroll
    for (int i = 0; i < 3; i++) {
        int nt = ns * 3 + i;
#pragma unroll
        for (int msI = 0; msI < 2; msI++) {
#pragma unroll
            for (int r = 0; r < 4; r++) {
                unsigned short bv = f2bf(acc[msI * 3 + i][r]);
                int off;
                int ch;
                if (nt < 4) {            // Q
                    ch  = msI * 2 + (nt >> 1);
                    off = (quad * 4 + r) * 32 + ((nt & 1) * 2 + (l16 >> 3)) * 8 + (l16 & 7);
                } else if (nt < 8) {     // K
                    int nk = nt - 4;
                    ch  = 4 + msI * 2 + (nk >> 1);
                    off = (quad * 4 + r) * 32 + ((nk & 1) * 2 + (l16 >> 3)) * 8 + (l16 & 7);
                } else {                 // V
                    int w32 = msI * 16 + quad * 4 + r;
                    ch  = 8 + (nt - 8);
                    off = l16 * 32 + (w32 >> 3) * 8 + (w32 & 7);
                }
                E[ch * 512 + off] = bv;
            }
        }
    }
    __syncthreads();

#pragma unroll
    for (int i = 0; i < 3; i++) {
        int gi = i * 256 + tid;          // 0..767
        int ch = gi >> 6;
        int g  = gi & 63;
        unsigned short* dst;
        if (ch < 4) {
            dst = Qf + ((size_t)(bb * 128 + t16_0 + (ch >> 1)) * 2 + (ch & 1)) * 512;
        } else if (ch < 8) {
            int c2 = ch - 4;
            dst = Kf + ((size_t)(bb * 128 + t16_0 + (c2 >> 1)) * 2 + (c2 & 1)) * 512;
        } else {
            dst = Vf + ((size_t)(bb * 64 + s32) * 4 + (ch - 8)) * 512;
        }
        *(u16x8*)(dst + g * 8) = *(const u16x8*)(&E[ch * 512 + g * 8]);
    }
}

// ---------------------------------------------------------------------------
// Kernel 2: flash attention, v8 (32 q-rows/block, 4-way KV split).
// Grid = B * T/32 = 512 blocks x 256 threads, XCD batch-affinity (b = blk&7).
// Two q-groups per block share every K/V fragment load (2x arithmetic
// intensity) and total KV tile re-read traffic halves vs v7.
// ---------------------------------------------------------------------------
#define PROW 33   // u32 per P^T row
#define OMS2 66   // u16 per O-merge row

__global__ __launch_bounds__(256) void attn(
        const unsigned short* __restrict__ Qf,
        const unsigned short* __restrict__ Kf,
        const unsigned short* __restrict__ Vf,
        float* __restrict__ out) {
    __shared__ unsigned int ps_[4 * 32 * PROW];     // 16.9 KB
    __shared__ unsigned short Om_[4 * 32 * OMS2];   // 16.9 KB
    __shared__ float mred_[4][32];
    __shared__ float lred_[4][32];

    const int tid  = threadIdx.x;
    const int wave = tid >> 6;            // KV-split index 0..3
    const int lane = tid & 63;
    const int l16  = lane & 15;
    const int quad = lane >> 4;
    const int b    = blockIdx.x & 7;      // XCD-affinity: batch = XCD
    const int qt32 = blockIdx.x >> 3;     // 0..63
    const int q0   = qt32 * 32;
    const int tdiag = qt32 >> 1;          // diagonal 64-key tile index

    const int loff = l16 * 32 + quad * 8;

    // Q as B-operand, two q-groups
    bf16x8 qf[2][2];
#pragma unroll
    for (int qg = 0; qg < 2; qg++) {
        const unsigned short* Qfb = Qf + (size_t)((b * 128 + qt32 * 2 + qg) * 2) * 512;
        qf[qg][0] = load8_bf(Qfb + loff);
        qf[qg][1] = load8_bf(Qfb + 512 + loff);
    }

    f32x4 o[8];   // [qg*4 + ht]
#pragma unroll
    for (int i = 0; i < 8; i++) o[i] = (f32x4){0.f, 0.f, 0.f, 0.f};
    float m_run[2] = {-1e30f, -1e30f}, l_run[2] = {0.f, 0.f};

    const float scale = 0.125f;  // 1/sqrt(H)
    const unsigned short* Kfb = Kf + (size_t)b * 128 * 1024;
    const unsigned short* Vfb = Vf + (size_t)b * 64 * 2048;
    unsigned int* Pw = &ps_[wave * 32 * PROW];

    for (int t = wave; t <= tdiag; t += 4) {
        // V^T A-frags: contiguous 1KB loads, issued EARLY (softmax-independent)
        bf16x8 vf[8];
#pragma unroll
        for (int ks = 0; ks < 2; ks++)
#pragma unroll
            for (int ht = 0; ht < 4; ht++)
                vf[ht * 2 + ks] = load8_bf(
                    Vfb + ((size_t)(t * 2 + ks) * 4 + ht) * 512 + loff);

        // S^T = K * Q^T for both q-groups (K frags shared)
        f32x4 s[2][4];
#pragma unroll
        for (int nt = 0; nt < 4; nt++) {
            const unsigned short* kp = Kfb + (size_t)(t * 4 + nt) * 1024;
            bf16x8 kf0 = load8_bf(kp + loff);
            bf16x8 kf1 = load8_bf(kp + 512 + loff);
#pragma unroll
            for (int qg = 0; qg < 2; qg++) {
                f32x4 z = (f32x4){0.f, 0.f, 0.f, 0.f};
                z = __builtin_amdgcn_mfma_f32_16x16x32_bf16(kf0, qf[qg][0], z, 0, 0, 0);
                z = __builtin_amdgcn_mfma_f32_16x16x32_bf16(kf1, qf[qg][1], z, 0, 0, 0);
                s[qg][nt] = z;   // S^T[s = t*64+nt*16+quad*4+r][q = q0+qg*16+l16]
            }
        }

#pragma unroll
        for (int qg = 0; qg < 2; qg++)
#pragma unroll
            for (int nt = 0; nt < 4; nt++)
#pragma unroll
                for (int r = 0; r < 4; r++) s[qg][nt][r] *= scale;

        if (t == tdiag) {   // causal: mask s > q
#pragma unroll
            for (int qg = 0; qg < 2; qg++) {
                int q = q0 + qg * 16 + l16;
#pragma unroll
                for (int nt = 0; nt < 4; nt++)
#pragma unroll
                    for (int r = 0; r < 4; r++) {
                        int key = t * 64 + nt * 16 + quad * 4 + r;
                        if (key > q) s[qg][nt][r] = -1e30f;
                    }
            }
        }

        // per-lane softmax per q-group: in-lane tree + 2 cross-quad shuffles
#pragma unroll
        for (int qg = 0; qg < 2; qg++) {
            float m0 = fmaxf(fmaxf(s[qg][0][0], s[qg][0][1]), fmaxf(s[qg][0][2], s[qg][0][3]));
            float m1 = fmaxf(fmaxf(s[qg][1][0], s[qg][1][1]), fmaxf(s[qg][1][2], s[qg][1][3]));
            float m2 = fmaxf(fmaxf(s[qg][2][0], s[qg][2][1]), fmaxf(s[qg][2][2], s[qg][2][3]));
            float m3 = fmaxf(fmaxf(s[qg][3][0], s[qg][3][1]), fmaxf(s[qg][3][2], s[qg][3][3]));
            float mx = fmaxf(fmaxf(m0, m1), fmaxf(m2, m3));
            mx = fmaxf(mx, __shfl_xor(mx, 16));
            mx = fmaxf(mx, __shfl_xor(mx, 32));
            const float m_new = fmaxf(m_run[qg], mx);
            const float alpha = __expf(m_run[qg] - m_new);
            m_run[qg] = m_new;

            float rs = 0.f;
#pragma unroll
            for (int nt = 0; nt < 4; nt++) {
#pragma unroll
                for (int i = 0; i < 2; i++) {
                    float p0 = __expf(s[qg][nt][2 * i]     - m_new);
                    float p1 = __expf(s[qg][nt][2 * i + 1] - m_new);
                    rs += p0 + p1;
                    Pw[(qg * 16 + l16) * PROW + nt * 8 + quad * 2 + i] = pack2(p0, p1);
                }
            }
            rs += __shfl_xor(rs, 16);
            rs += __shfl_xor(rs, 32);
            l_run[qg] = l_run[qg] * alpha + rs;

#pragma unroll
            for (int ht = 0; ht < 4; ht++)
#pragma unroll
                for (int r = 0; r < 4; r++) o[qg * 4 + ht][r] *= alpha;
        }

        // O^T += V^T * P^T (V frags shared across q-groups)
#pragma unroll
        for (int ks = 0; ks < 2; ks++) {
#pragma unroll
            for (int qg = 0; qg < 2; qg++) {
                bf16x8 pB = __builtin_bit_cast(bf16x8,
                    *(const u16x8*)(&Pw[(qg * 16 + l16) * PROW + ks * 16 + quad * 4]));
#pragma unroll
                for (int ht = 0; ht < 4; ht++)
                    o[qg * 4 + ht] = __builtin_amdgcn_mfma_f32_16x16x32_bf16(
                        vf[ht * 2 + ks], pB, o[qg * 4 + ht], 0, 0, 0);
            }
        }
    }

    // ---- 4-way LSE merge (O partials bf16) ----
#pragma unroll
    for (int qg = 0; qg < 2; qg++) {
#pragma unroll
        for (int ht = 0; ht < 4; ht++)
#pragma unroll
            for (int r = 0; r < 4; r++)
                Om_[(wave * 32 + qg * 16 + l16) * OMS2 + ht * 16 + quad * 4 + r] =
                    f2bf(o[qg * 4 + ht][r]);
        if (quad == 0) {
            mred_[wave][qg * 16 + l16] = m_run[qg];
            lred_[wave][qg * 16 + l16] = l_run[qg];
        }
    }
    __syncthreads();

    // finalize: thread -> (q, h); coalesced out write
    const int hcol = tid & 63;
    const int qr0  = tid >> 6;   // 0..3
#pragma unroll
    for (int qq = 0; qq < 8; qq++) {
        const int q = qr0 + qq * 4;
        float M = -1e30f;
#pragma unroll
        for (int w = 0; w < 4; w++) M = fmaxf(M, mred_[w][q]);
        float lt = 0.f, ov = 0.f;
#pragma unroll
        for (int w = 0; w < 4; w++) {
            float e = __expf(mred_[w][q] - M);
            lt += e * lred_[w][q];
            ov += e * bf2f(Om_[(w * 32 + q) * OMS2 + hcol]);
        }
        out[((size_t)b * T_ + q0 + q) * H_ + hcol] = ov / lt;
    }
}

// ---------------------------------------------------------------------------
extern "C" void kernel_launch(void* const* d_in, const int* in_sizes, int n_in,
                              void* d_out, int out_size, void* d_ws, size_t ws_size,
                              hipStream_t stream) {
    const float* x  = (const float*)d_in[0];
    const float* Wq = (const float*)d_in[1];
    const float* Wk = (const float*)d_in[2];
    const float* Wv = (const float*)d_in[3];
    float* out = (float*)d_out;

    unsigned short* Qf  = (unsigned short*)d_ws;
    unsigned short* Kf  = Qf + (size_t)B_ * T_ * H_;
    unsigned short* Vf  = Kf + (size_t)B_ * T_ * H_;
    unsigned short* Wtf = Vf + (size_t)B_ * T_ * H_;

    cast_weights<<<(192 * C_) / 256, 256, 0, stream>>>(Wq, Wk, Wv, Wtf);
    qkv_proj<<<B_ * T_ / 32, 256, 0, stream>>>(x, Wtf, Qf, Kf, Vf);
    attn<<<B_ * (T_ / 32), 256, 0, stream>>>(Qf, Kf, Vf, out);
}